// Round 16
// baseline (266.191 us; speedup 1.0000x reference)
//
#include <hip/hip_runtime.h>
#include <stdint.h>
#include <math.h>

#define S_LEN 2048
#define HID 2048
#define NH 16
#define HD 128
#define NROWS 4096  // B*S
#define SCALE 0.08838834764831845f
#define C2 (0.08838834764831845f * 1.442695040888963f)  // SCALE * log2(e)

typedef unsigned short u16;
typedef __attribute__((ext_vector_type(8))) short short8;
typedef __attribute__((ext_vector_type(4))) float f32x4;
typedef __attribute__((ext_vector_type(16))) float f32x16;
typedef __attribute__((ext_vector_type(4))) unsigned short u16x4;
typedef __attribute__((ext_vector_type(4))) unsigned int u32x4;
typedef __attribute__((ext_vector_type(4))) float float4v;

__device__ __forceinline__ u16 f2bf(float f) {
  union { float f; uint32_t u; } v; v.f = f;
  uint32_t r = v.u + 0x7FFFu + ((v.u >> 16) & 1u);
  return (u16)(r >> 16);
}
__device__ __forceinline__ float bf2f(u16 b) {
  union { uint32_t u; float f; } v; v.u = ((uint32_t)b) << 16;
  return v.f;
}
__device__ __forceinline__ void gl_lds16(const void* g, void* l) {
  __builtin_amdgcn_global_load_lds((const __attribute__((address_space(1))) void*)g,
                                   (__attribute__((address_space(3))) void*)l, 16, 0, 0);
}
__device__ __forceinline__ unsigned cvtpk(float lo, float hi) {
  unsigned r;
  asm("v_cvt_pk_bf16_f32 %0, %1, %2" : "=v"(r) : "v"(lo), "v"(hi));
  return r;
}
__device__ __forceinline__ void plswap(unsigned &a, unsigned &b) {
  asm volatile("v_permlane32_swap_b32 %0, %1" : "+v"(a), "+v"(b));
}

// ---------- merged pre-pass: rmsnorm (blocks 0..4095) + wconv4 (blocks 4096..8191) ----------
__global__ __launch_bounds__(256) void k_pre(const float* __restrict__ x, const float* __restrict__ rw,
                                             u16* __restrict__ xn,
                                             const float* __restrict__ w0, const float* __restrict__ w1,
                                             const float* __restrict__ w2, const float* __restrict__ w3,
                                             u16* __restrict__ wtbase) {
  int bid = blockIdx.x;
  int tid = threadIdx.x;
  if (bid < 4096) {
    int row = bid;
    const float* xr = x + (size_t)row * HID;
    float4v a = *(const float4v*)(xr + tid * 8);
    float4v b = *(const float4v*)(xr + tid * 8 + 4);
    float s = a[0]*a[0] + a[1]*a[1] + a[2]*a[2] + a[3]*a[3]
            + b[0]*b[0] + b[1]*b[1] + b[2]*b[2] + b[3]*b[3];
    #pragma unroll
    for (int off = 1; off < 64; off <<= 1) s += __shfl_xor(s, off, 64);
    __shared__ float red[4];
    int wv = tid >> 6;
    if ((tid & 63) == 0) red[wv] = s;
    __syncthreads();
    float tot = red[0] + red[1] + red[2] + red[3];
    float r = rsqrtf(tot * (1.0f / HID) + 1e-5f);
    const float* wp = rw + tid * 8;
    u16x4 o0, o1;
    #pragma unroll
    for (int j = 0; j < 4; ++j) { o0[j] = f2bf(a[j] * r * wp[j]); o1[j] = f2bf(b[j] * r * wp[4 + j]); }
    *(u16x4*)(xn + (size_t)row * HID + tid * 8) = o0;
    *(u16x4*)(xn + (size_t)row * HID + tid * 8 + 4) = o1;
  } else {
    int c = bid - 4096;
    int z = c >> 10;
    int rest = c & 1023;
    int n0 = (rest & 31) * 64, k0 = (rest >> 5) * 64;
    const float* w = (z == 0) ? w0 : (z == 1) ? w1 : (z == 2) ? w2 : w3;
    u16* wt = wtbase + (size_t)z * HID * HID;
    __shared__ float t[64][68];
    int cr = tid >> 4;
    int cc = (tid & 15) * 4;
    #pragma unroll
    for (int it = 0; it < 4; ++it) {
      int kk = cr + it * 16;
      float4v v = *(const float4v*)(w + (size_t)(k0 + kk) * HID + n0 + cc);
      t[kk][cc] = v[0]; t[kk][cc + 1] = v[1]; t[kk][cc + 2] = v[2]; t[kk][cc + 3] = v[3];
    }
    __syncthreads();
    #pragma unroll
    for (int it = 0; it < 4; ++it) {
      int nn = cr + it * 16;
      u16x4 o;
      #pragma unroll
      for (int j = 0; j < 4; ++j) o[j] = f2bf(t[cc + j][nn]);
      *(u16x4*)(wt + (size_t)(n0 + nn) * HID + k0 + cc) = o;
    }
  }
}

// ---------- merged post-pass: ropepack (blocks 0..4095) + vpack (blocks 4096..5119) ----------
__global__ __launch_bounds__(256) void k_post(const u16* __restrict__ qh, const u16* __restrict__ kh,
                                              u16* __restrict__ QP, u16* __restrict__ KP,
                                              const u16* __restrict__ vh, u16* __restrict__ VP) {
  int bid = blockIdx.x;
  int tid = threadIdx.x;
  if (bid < 4096) {
    int l = tid & 63, wvv = tid >> 6;
    int rsub = l >> 4, c = l & 15;
    int row = bid * 16 + wvv * 4 + rsub;   // bh*2048 + s
    int bh = row >> 11, s = row & 2047;
    int tile = s >> 5, ln = s & 31;
    int ks = c >> 1, hi = c & 1;
    int k3 = ks & 3;
    const u16* qi = qh + (size_t)row * HD + 32 * k3 + 16 * hi;
    const u16* ki = kh + (size_t)row * HD + 32 * k3 + 16 * hi;
    float sn[8], cs[8];
    #pragma unroll
    for (int j = 0; j < 8; ++j) {
      int de = 16 * k3 + 8 * hi + j;
      float freq = exp2f((float)de * -0.20762050593046014f);  // theta^(-de/64)
      sincosf((float)s * freq, &sn[j], &cs[j]);
    }
    size_t off = ((((size_t)(bh * 64 + tile)) * 8 + ks) * 64 + hi * 32 + ln) * 8;
    {
      short8 a = *(const short8*)(qi);
      short8 b2 = *(const short8*)(qi + 8);
      u16x4 o0, o1;
      #pragma unroll
      for (int j = 0; j < 4; ++j) {
        float x0 = bf2f((u16)a[2 * j]), x1 = bf2f((u16)a[2 * j + 1]);
        o0[j] = f2bf((j & 1) ? (sn[j] * x0 + cs[j] * x1) : (cs[j] * x0 - sn[j] * x1));
      }
      #pragma unroll
      for (int j = 0; j < 4; ++j) {
        int jj = j + 4;
        float x0 = bf2f((u16)b2[2 * j]), x1 = bf2f((u16)b2[2 * j + 1]);
        o1[j] = f2bf((jj & 1) ? (sn[jj] * x0 + cs[jj] * x1) : (cs[jj] * x0 - sn[jj] * x1));
      }
      *(u16x4*)(QP + off) = o0; *(u16x4*)(QP + off + 4) = o1;
    }
    {
      short8 a = *(const short8*)(ki);
      short8 b2 = *(const short8*)(ki + 8);
      u16x4 o0, o1;
      #pragma unroll
      for (int j = 0; j < 4; ++j) {
        float x0 = bf2f((u16)a[2 * j]), x1 = bf2f((u16)a[2 * j + 1]);
        o0[j] = f2bf((j & 1) ? (sn[j] * x0 + cs[j] * x1) : (cs[j] * x0 - sn[j] * x1));
      }
      #pragma unroll
      for (int j = 0; j < 4; ++j) {
        int jj = j + 4;
        float x0 = bf2f((u16)b2[2 * j]), x1 = bf2f((u16)b2[2 * j + 1]);
        o1[j] = f2bf((jj & 1) ? (sn[jj] * x0 + cs[jj] * x1) : (cs[jj] * x0 - sn[jj] * x1));
      }
      *(u16x4*)(KP + off) = o0; *(u16x4*)(KP + off + 4) = o1;
    }
  } else {
    int c = bid - 4096;           // 0..1023
    int bx = c & 31;              // s-tile of 64
    int bh = c >> 5;
    __shared__ u16 t[64][136];
    int row = tid >> 2;
    int d0 = (tid & 3) * 32;
    const u16* src = vh + ((size_t)bh * S_LEN + bx * 64 + row) * HD + d0;
    short8 a = *(const short8*)(src);
    short8 b = *(const short8*)(src + 8);
    short8 cc2 = *(const short8*)(src + 16);
    short8 d = *(const short8*)(src + 24);
    *(short8*)(&t[row][d0]) = a;
    *(short8*)(&t[row][d0 + 8]) = b;
    *(short8*)(&t[row][d0 + 16]) = cc2;
    *(short8*)(&t[row][d0 + 24]) = d;
    __syncthreads();
    #pragma unroll
    for (int i = 0; i < 4; ++i) {
      int cid = i * 256 + tid;        // chunk id 0..1023
      int lp = cid & 63;
      int db = (cid >> 6) & 3;
      int j2 = (cid >> 8) & 1;
      int tl = (cid >> 9) & 1;
      int tg = bx * 2 + tl;
      int tloc = tl * 32 + j2 * 16 + (lp >> 5) * 8;
      int dloc = db * 32 + (lp & 31);
      short8 v;
      #pragma unroll
      for (int jj = 0; jj < 8; ++jj) v[jj] = (short)t[tloc + jj][dloc];
      size_t off = ((((size_t)(bh * 64 + tg) * 2 + j2) * 4 + db) * 64 + lp) * 8;
      *(short8*)(VP + off) = v;
    }
  }
}

// ---------- pipelined QKV GEMM: C[4096][6144] = A[4096][2048] * BT[6144][2048] ----------
// BM=128, BN=256, 8 waves (2x4), per-wave 64x64. K regions of 32, 3-slot LDS ring (72 KB
// -> 2 blocks/CU), counted vmcnt(3) (tail 0), one raw s_barrier per phase.
// bx-major block mapping: resident blocks per XCD share 2 B-panels (2 MB, L2-resident).
__global__ __launch_bounds__(512, 2) void k_gemm_qkv2(const u16* __restrict__ A, const u16* __restrict__ BT,
                                                      const float* __restrict__ bq, const float* __restrict__ bk,
                                                      const float* __restrict__ bv, u16* __restrict__ qkv) {
  extern __shared__ __align__(16) char smraw[];
  u16* sm = (u16*)smraw;     // 3 slots x 12288 u16 (A:4096 + B:8192)
  int bid = blockIdx.x;      // 768 blocks
  int xcd = bid & 7, loc = bid >> 3;   // loc 0..95
  int bx = xcd * 3 + loc / 32;    // 0..23 (N-block of 256); bx-major for B L2 residency
  int by = loc % 32;              // 0..31 (M-block of 128)
  int tid = threadIdx.x;
  int w = tid >> 6, lane = tid & 63;
  int wr = w >> 2, wc = w & 3;    // 2 x 4 waves
  int lq = lane & 15, lg = lane >> 4;

  f32x4 acc[4][4];
  #pragma unroll
  for (int mi = 0; mi < 4; ++mi)
    #pragma unroll
    for (int ni = 0; ni < 4; ++ni) acc[mi][ni] = (f32x4){0.f, 0.f, 0.f, 0.f};

  const size_t Abase = (size_t)(by * 128) * HID;
  const size_t Bbase = (size_t)(bx * 256) * HID;

  // stage region n (k = n*32 .. n*32+32) into slot n%3; source-side swizzle chunk^=(row>>1)&3
  #define STAGE_Q(n)  do { \
    int slot_ = ((n) % 3) * 12288; \
    int kb_ = (n) * 32; \
    { int c_ = tid; int row_ = c_ >> 2; int ch_ = (c_ & 3) ^ ((row_ >> 1) & 3); \
      gl_lds16(A + Abase + (size_t)row_ * HID + kb_ + ch_ * 8, sm + slot_ + c_ * 8); } \
    _Pragma("unroll") \
    for (int it_ = 0; it_ < 2; ++it_) { \
      int c_ = it_ * 512 + tid; int row_ = c_ >> 2; int ch_ = (c_ & 3) ^ ((row_ >> 1) & 3); \
      gl_lds16(BT + Bbase + (size_t)row_ * HID + kb_ + ch_ * 8, sm + slot_ + 4096 + c_ * 8); } \
  } while (0)

  STAGE_Q(0); STAGE_Q(1);
  asm volatile("s_waitcnt vmcnt(3)" ::: "memory");
  __builtin_amdgcn_s_barrier();
  __builtin_amdgcn_sched_barrier(0);

  for (int n = 0; n < 64; ++n) {
    if (n + 2 <= 63) STAGE_Q(n + 2);
    int slot = (n % 3) * 12288;
    const u16* sA = sm + slot;
    const u16* sB = sm + slot + 4096;
    short8 af[4], bf[4];
    #pragma unroll
    for (int mi = 0; mi < 4; ++mi) {
      int ra = wr * 64 + mi * 16 + lq;
      af[mi] = *(const short8*)(sA + ra * 32 + ((lg ^ ((ra >> 1) & 3)) << 3));
    }
    #pragma unroll
    for (int ni = 0; ni < 4; ++ni) {
      int rb = wc * 64 + ni * 16 + lq;
      bf[ni] = *(const short8*)(sB + rb * 32 + ((lg ^ ((rb >> 1) & 3)) << 3));
    }
    __builtin_amdgcn_s_setprio(1);
    #pragma unroll
    for (int mi = 0; mi < 4; ++mi)
      #pragma unroll
      for (int ni = 0; ni < 4; ++ni)
        acc[mi][ni] = __builtin_amdgcn_mfma_f32_16x16x32_bf16(af[mi], bf[ni], acc[mi][ni], 0, 0, 0);
    __builtin_amdgcn_s_setprio(0);
    if (n <= 61) {
      asm volatile("s_waitcnt vmcnt(3)" ::: "memory");
      __builtin_amdgcn_s_barrier();
      __builtin_amdgcn_sched_barrier(0);
    } else if (n == 62) {
      asm volatile("s_waitcnt vmcnt(0)" ::: "memory");
      __builtin_amdgcn_s_barrier();
      __builtin_amdgcn_sched_barrier(0);
    }
  }

  #pragma unroll
  for (int ni = 0; ni < 4; ++ni) {
    int colg = bx * 256 + wc * 64 + ni * 16 + lq;   // 0..6143
    int sel = colg >> 11;
    int col = colg & 2047;
    int h = col >> 7, d = col & 127;
    const float* bias = (sel == 0) ? bq : (sel == 1) ? bk : bv;
    float bs = bias[col];
    u16* outp = qkv + (size_t)sel * NROWS * HID;
    #pragma unroll
    for (int mi = 0; mi < 4; ++mi) {
      #pragma unroll
      for (int r = 0; r < 4; ++r) {
        int rowm = by * 128 + wr * 64 + mi * 16 + lg * 4 + r;
        int b = rowm >> 11, s = rowm & 2047;
        outp[(((size_t)(b * NH + h)) * S_LEN + s) * HD + d] = f2bf(acc[mi][ni][r] + bs);
      }
    }
  }
  #undef STAGE_Q
}

// ---------- pipelined output GEMM: C[4096][2048] f32 = A*BT + bias + resid ----------
// BM=BN=128, 4 waves (2x2), 3-slot 48 KB ring -> 3 blocks/CU; grid 512 (2/CU co-resident).
__global__ __launch_bounds__(256, 3) void k_gemm_o2(const u16* __restrict__ A, const u16* __restrict__ BT,
                                                    const float* __restrict__ bias,
                                                    const float* __restrict__ resid,
                                                    float* __restrict__ outp) {
  extern __shared__ __align__(16) char smraw[];
  u16* sm = (u16*)smraw;     // 3 slots x 8192 u16 (A:4096 + B:4096)
  int bid = blockIdx.x;      // 512 blocks
  int xcd = bid & 7, loc = bid >> 3;   // loc 0..63
  int bx = xcd * 2 + (loc & 1);  // 0..15 (N-block of 128)
  int by = loc >> 1;             // 0..31
  int tid = threadIdx.x;
  int w = tid >> 6, lane = tid & 63;
  int wr = w >> 1, wc = w & 1;
  int lq = lane & 15, lg = lane >> 4;

  f32x4 acc[4][4];
  #pragma unroll
  for (int mi = 0; mi < 4; ++mi)
    #pragma unroll
    for (int ni = 0; ni < 4; ++ni) acc[mi][ni] = (f32x4){0.f, 0.f, 0.f, 0.f};

  const size_t Abase = (size_t)(by * 128) * HID;
  const size_t Bbase = (size_t)(bx * 128) * HID;

  #define STAGE_O(n)  do { \
    int slot_ = ((n) % 3) * 8192; \
    int kb_ = (n) * 32; \
    _Pragma("unroll") \
    for (int it_ = 0; it_ < 2; ++it_) { \
      int c_ = it_ * 256 + tid; int row_ = c_ >> 2; int ch_ = (c_ & 3) ^ ((row_ >> 1) & 3); \
      gl_lds16(A + Abase + (size_t)row_ * HID + kb_ + ch_ * 8, sm + slot_ + c_ * 8); } \
    _Pragma("unroll") \
    for (int it_ = 0; it_ < 2; ++it_) { \
      int c_ = it_ * 256 + tid; int row_ = c_ >> 2; int ch_ = (c_ & 3) ^ ((row_ >> 1) & 3); \
      gl_lds16(BT + Bbase + (size_t)row_ * HID + kb_ + ch_ * 8, sm + slot_ + 4096 + c_ * 8); } \
  } while (0)

  STAGE_O(0); STAGE_O(1);
  asm volatile("s_waitcnt vmcnt(4)" ::: "memory");
  __builtin_amdgcn_s_barrier();
  __builtin_amdgcn_sched_barrier(0);

  for (int n = 0; n < 64; ++n) {
    if (n + 2 <= 63) STAGE_O(n + 2);
    int slot = (n % 3) * 8192;
    const u16* sA = sm + slot;
    const u16* sB = sm + slot + 4096;
    short8 af[4], bf[4];
    #pragma unroll
    for (int mi = 0; mi < 4; ++mi) {
      int ra = wr * 64 + mi * 16 + lq;
      af[mi] = *(const short8*)(sA + ra * 32 + ((lg ^ ((ra >> 1) & 3)) << 3));
    }
    #pragma unroll
    for (int ni = 0; ni < 4; ++ni) {
      int rb = wc * 64 + ni * 16 + lq;
      bf[ni] = *(const short8*)(sB + rb * 32 + ((lg ^ ((rb >> 1) & 3)) << 3));
    }
    __builtin_amdgcn_s_setprio(1);
    #pragma unroll
    for (int mi = 0; mi < 4; ++mi)
      #pragma unroll
      for (int ni = 0; ni < 4; ++ni)
        acc[mi][ni] = __builtin_amdgcn_mfma_f32_16x16x32_bf16(af[mi], bf[ni], acc[mi][ni], 0, 0, 0);
    __builtin_amdgcn_s_setprio(0);
    if (n <= 61) {
      asm volatile("s_waitcnt vmcnt(4)" ::: "memory");
      __builtin_amdgcn_s_barrier();
      __builtin_amdgcn_sched_barrier(0);
    } else if (n == 62) {
      asm volatile("s_waitcnt vmcnt(0)" ::: "memory");
      __builtin_amdgcn_s_barrier();
      __builtin_amdgcn_sched_barrier(0);
    }
  }

  #pragma unroll
  for (int ni = 0; ni < 4; ++ni) {
    int col = bx * 128 + wc * 64 + ni * 16 + lq;
    float bs = bias[col];
    #pragma unroll
    for (int mi = 0; mi < 4; ++mi) {
      #pragma unroll
      for (int r = 0; r < 4; ++r) {
        int rowm = by * 128 + wr * 64 + mi * 16 + lg * 4 + r;
        size_t o = (size_t)rowm * HID + col;
        outp[o] = acc[mi][ni][r] + bs + resid[o];
      }
    }
  }
  #undef STAGE_O
}

// ---------- flash attention v6: barrier-free, LDS-free, packed fragment loads ----------
// QP,KP: [bh][tile][ks(8)][lane][8]; VP: [bh][tile][j2(2)][db(4)][lane][8]; out bf16 [b][s][h*128+d]
__global__ __launch_bounds__(64, 2) void k_attn(const u16* __restrict__ QP, const u16* __restrict__ KP,
                                                const u16* __restrict__ VP, u16* __restrict__ out) {
  int bid = blockIdx.x;            // 2048 one-wave blocks
  int rest = bid >> 3;
  int bh = (bid & 7) * 4 + (rest & 3);   // 4 heads per XCD
  int gg = rest >> 2;                    // 0..63
  int qw = (gg < 32) ? (63 - gg) : (gg - 32);  // complement-paired for balance
  int b = bh >> 4, h = bh & 15;
  int lane = threadIdx.x;
  int hi = lane >> 5, ln = lane & 31;
  int q0 = qw * 32, qrow = q0 + ln;

  const u16* QPb = QP + ((size_t)(bh * 64 + qw) * 8) * 512 + lane * 8;
  short8 qf[8];
  #pragma unroll
  for (int ks = 0; ks < 8; ++ks) qf[ks] = *(const short8*)(QPb + ks * 512);

  f32x16 oc[4];
  #pragma unroll
  for (int db = 0; db < 4; ++db)
    #pragma unroll
    for (int r = 0; r < 16; ++r) oc[db][r] = 0.f;
  float mr = -3.0e38f, l = 0.f;

  const u16* KPb = KP + ((size_t)bh * 64 * 8) * 512 + lane * 8;  // + tt*4096 + ks*512
  const u16* VPb = VP + ((size_t)bh * 64 * 8) * 512 + lane * 8;  // + tt*4096 + (j2*4+db)*512

  int ntile = qw + 1;
  short8 kf[8];
  #pragma unroll
  for (int ks = 0; ks < 8; ++ks) kf[ks] = *(const short8*)(KPb + ks * 512);  // tile 0

  for (int tt = 0; tt < ntile; ++tt) {
    // V fragments for this tile (consumed after softmax — latency hidden)
    short8 va[8];
    #pragma unroll
    for (int u = 0; u < 8; ++u) va[u] = *(const short8*)(VPb + (size_t)tt * 4096 + u * 512);

    // S^T = K · Q
    f32x16 st;
    #pragma unroll
    for (int r = 0; r < 16; ++r) st[r] = 0.f;
    __builtin_amdgcn_s_setprio(1);
    #pragma unroll
    for (int ks = 0; ks < 8; ++ks)
      st = __builtin_amdgcn_mfma_f32_32x32x16_bf16(kf[ks], qf[ks], st, 0, 0, 0);
    __builtin_amdgcn_s_setprio(0);

    // prefetch next K tile (lands during softmax + PV)
    if (tt + 1 < ntile) {
      #pragma unroll
      for (int ks = 0; ks < 8; ++ks)
        kf[ks] = *(const short8*)(KPb + (size_t)(tt + 1) * 4096 + ks * 512);
    }

    int t0 = tt * 32;
    float sv[16];
    float pm = -3.0e38f;
    bool lastt = (tt == ntile - 1);
    #pragma unroll
    for (int r = 0; r < 16; ++r) {
      float x = st[r];
      if (lastt) {
        int t = t0 + (r & 3) + 8 * (r >> 2) + 4 * hi;
        x = (t <= qrow) ? x : -3.0e38f;
      }
      sv[r] = x;
    }
    #pragma unroll
    for (int r = 0; r < 15; r += 2) pm = fmaxf(fmaxf(pm, sv[r]), sv[r + 1]);
    pm = fmaxf(pm, sv[15]);
    pm = fmaxf(pm, __shfl_xor(pm, 32, 64));
    if (!__all(pm <= mr + 64.0f)) {
      float mnew = fmaxf(mr, pm);
      float al = exp2f((mr - mnew) * C2);
      l *= al;
      #pragma unroll
      for (int db = 0; db < 4; ++db)
        #pragma unroll
        for (int r = 0; r < 16; ++r) oc[db][r] *= al;
      mr = mnew;
    }
    float mc = mr * C2;
    float e[16];
    float rs = 0.f;
    #pragma unroll
    for (int r = 0; r < 16; ++r) {
      e[r] = exp2f(fmaf(sv[r], C2, -mc));
      rs += e[r];
    }
    rs += __shfl_xor(rs, 32, 64);
    l += rs;

    // P -> bf16 B-frags in-register (cvt_pk + permlane32_swap)
    unsigned w0 = cvtpk(e[0], e[1]),   w1 = cvtpk(e[2], e[3]);
    unsigned w2 = cvtpk(e[4], e[5]),   w3 = cvtpk(e[6], e[7]);
    unsigned w4 = cvtpk(e[8], e[9]),   w5 = cvtpk(e[10], e[11]);
    unsigned w6 = cvtpk(e[12], e[13]), w7 = cvtpk(e[14], e[15]);
    plswap(w0, w2); plswap(w1, w3); plswap(w4, w6); plswap(w5, w7);
    u32x4 pw0 = {w0, w1, w2, w3};
    u32x4 pw1 = {w4, w5, w6, w7};
    short8 pb0 = __builtin_bit_cast(short8, pw0);
    short8 pb1 = __builtin_bit_cast(short8, pw1);

    // O^T += V^T · P
    __builtin_amdgcn_s_setprio(1);
    #pragma unroll
    for (int db = 0; db < 4; ++db)
      oc[db] = __builtin_amdgcn_mfma_f32_32x32x16_bf16(va[db], pb0, oc[db], 0, 0, 0);
    #pragma unroll
    for (int db = 0; db < 4; ++db)
      oc[db] = __builtin_amdgcn_mfma_f32_32x32x16_bf16(va[4 + db], pb1, oc[db], 0, 0, 0);
    __builtin_amdgcn_s_setprio(0);
  }

  // epilogue: out[b][s=qrow][h*128 + d], d = db*32 + 8g + 4hi + j
  float inv = 1.0f / l;
  size_t ob = ((size_t)(b * S_LEN + qrow)) * HID + h * HD;
  #pragma unroll
  for (int db = 0; db < 4; ++db) {
    #pragma unroll
    for (int g = 0; g < 4; ++g) {
      u16x4 pk;
      #pragma unroll
      for (int j = 0; j < 4; ++j) pk[j] = f2bf(oc[db][4 * g + j] * inv);
      *(u16x4*)(out + ob + db * 32 + 8 * g + 4 * hi) = pk;
    }
  }
}

extern "C" void kernel_launch(void* const* d_in, const int* in_sizes, int n_in,
                              void* d_out, int out_size, void* d_ws, size_t ws_size,
                              hipStream_t stream) {
  const float* x    = (const float*)d_in[0];
  const float* rmsw = (const float*)d_in[1];
  const float* wq   = (const float*)d_in[2];
  const float* bq   = (const float*)d_in[3];
  const float* wk   = (const float*)d_in[4];
  const float* bk   = (const float*)d_in[5];
  const float* wv   = (const float*)d_in[6];
  const float* bv   = (const float*)d_in[7];
  const float* wo   = (const float*)d_in[8];
  const float* bo   = (const float*)d_in[9];

  char* ws = (char*)d_ws;
  const size_t SZ = (size_t)NROWS * HID * 2;  // 16 MB bf16 activation
  const size_t WSZ = (size_t)HID * HID * 2;   // 8 MB bf16 weight
  u16* xn   = (u16*)(ws);                     // 0-16 MB;  reused as QP
  u16* wqkT = (u16*)(ws + SZ);                // 16-40 MB; first 16 MB reused as KP
  u16* woT  = (u16*)(ws + SZ + 3 * WSZ);      // 40-48 MB, live till end
  u16* qhm  = (u16*)(ws + SZ + 4 * WSZ);      // 48-64 MB; reused as ao
  u16* khm  = (u16*)(ws + SZ + 4 * WSZ + SZ); // 64-80 MB; reused as VP
  u16* vhm  = (u16*)(ws + SZ + 4 * WSZ + 2 * SZ);  // 80-96 MB
  u16* QP   = xn;
  u16* KP   = wqkT;
  u16* VP   = khm;   // khm dead after ropepack
  u16* ao   = qhm;   // qhm dead after ropepack

  k_pre<<<dim3(8192), dim3(256), 0, stream>>>(x, rmsw, xn, wq, wk, wv, wo, wqkT);
  k_gemm_qkv2<<<dim3(768), dim3(512), 73728, stream>>>(xn, wqkT, bq, bk, bv, qhm);
  k_post<<<dim3(5120), dim3(256), 0, stream>>>(qhm, khm, QP, KP, vhm, VP);
  k_attn<<<dim3(2048), dim3(64), 0, stream>>>(QP, KP, VP, ao);
  k_gemm_o2<<<dim3(512), dim3(256), 49152, stream>>>(ao, woT, bo, x, (float*)d_out);
}

// Round 17
// 263.589 us; speedup vs baseline: 1.0099x; 1.0099x over previous
//
#include <hip/hip_runtime.h>
#include <stdint.h>
#include <math.h>

#define S_LEN 2048
#define HID 2048
#define NH 16
#define HD 128
#define NROWS 4096  // B*S
#define SCALE 0.08838834764831845f
#define C2 (0.08838834764831845f * 1.442695040888963f)  // SCALE * log2(e)

typedef unsigned short u16;
typedef __attribute__((ext_vector_type(8))) short short8;
typedef __attribute__((ext_vector_type(4))) float f32x4;
typedef __attribute__((ext_vector_type(16))) float f32x16;
typedef __attribute__((ext_vector_type(4))) unsigned short u16x4;
typedef __attribute__((ext_vector_type(4))) unsigned int u32x4;
typedef __attribute__((ext_vector_type(4))) float float4v;

__device__ __forceinline__ u16 f2bf(float f) {
  union { float f; uint32_t u; } v; v.f = f;
  uint32_t r = v.u + 0x7FFFu + ((v.u >> 16) & 1u);
  return (u16)(r >> 16);
}
__device__ __forceinline__ float bf2f(u16 b) {
  union { uint32_t u; float f; } v; v.u = ((uint32_t)b) << 16;
  return v.f;
}
__device__ __forceinline__ void gl_lds16(const void* g, void* l) {
  __builtin_amdgcn_global_load_lds((const __attribute__((address_space(1))) void*)g,
                                   (__attribute__((address_space(3))) void*)l, 16, 0, 0);
}
__device__ __forceinline__ unsigned cvtpk(float lo, float hi) {
  unsigned r;
  asm("v_cvt_pk_bf16_f32 %0, %1, %2" : "=v"(r) : "v"(lo), "v"(hi));
  return r;
}
__device__ __forceinline__ void plswap(unsigned &a, unsigned &b) {
  asm volatile("v_permlane32_swap_b32 %0, %1" : "+v"(a), "+v"(b));
}

// ---------- merged pre-pass: rmsnorm (blocks 0..4095) + wconv4 (blocks 4096..8191) ----------
__global__ __launch_bounds__(256) void k_pre(const float* __restrict__ x, const float* __restrict__ rw,
                                             u16* __restrict__ xn,
                                             const float* __restrict__ w0, const float* __restrict__ w1,
                                             const float* __restrict__ w2, const float* __restrict__ w3,
                                             u16* __restrict__ wtbase) {
  int bid = blockIdx.x;
  int tid = threadIdx.x;
  if (bid < 4096) {
    int row = bid;
    const float* xr = x + (size_t)row * HID;
    float4v a = *(const float4v*)(xr + tid * 8);
    float4v b = *(const float4v*)(xr + tid * 8 + 4);
    float s = a[0]*a[0] + a[1]*a[1] + a[2]*a[2] + a[3]*a[3]
            + b[0]*b[0] + b[1]*b[1] + b[2]*b[2] + b[3]*b[3];
    #pragma unroll
    for (int off = 1; off < 64; off <<= 1) s += __shfl_xor(s, off, 64);
    __shared__ float red[4];
    int wv = tid >> 6;
    if ((tid & 63) == 0) red[wv] = s;
    __syncthreads();
    float tot = red[0] + red[1] + red[2] + red[3];
    float r = rsqrtf(tot * (1.0f / HID) + 1e-5f);
    const float* wp = rw + tid * 8;
    u16x4 o0, o1;
    #pragma unroll
    for (int j = 0; j < 4; ++j) { o0[j] = f2bf(a[j] * r * wp[j]); o1[j] = f2bf(b[j] * r * wp[4 + j]); }
    *(u16x4*)(xn + (size_t)row * HID + tid * 8) = o0;
    *(u16x4*)(xn + (size_t)row * HID + tid * 8 + 4) = o1;
  } else {
    int c = bid - 4096;
    int z = c >> 10;
    int rest = c & 1023;
    int n0 = (rest & 31) * 64, k0 = (rest >> 5) * 64;
    const float* w = (z == 0) ? w0 : (z == 1) ? w1 : (z == 2) ? w2 : w3;
    u16* wt = wtbase + (size_t)z * HID * HID;
    __shared__ float t[64][68];
    int cr = tid >> 4;
    int cc = (tid & 15) * 4;
    #pragma unroll
    for (int it = 0; it < 4; ++it) {
      int kk = cr + it * 16;
      float4v v = *(const float4v*)(w + (size_t)(k0 + kk) * HID + n0 + cc);
      t[kk][cc] = v[0]; t[kk][cc + 1] = v[1]; t[kk][cc + 2] = v[2]; t[kk][cc + 3] = v[3];
    }
    __syncthreads();
    #pragma unroll
    for (int it = 0; it < 4; ++it) {
      int nn = cr + it * 16;
      u16x4 o;
      #pragma unroll
      for (int j = 0; j < 4; ++j) o[j] = f2bf(t[cc + j][nn]);
      *(u16x4*)(wt + (size_t)(n0 + nn) * HID + k0 + cc) = o;
    }
  }
}

// ---------- merged post-pass: ropepack (blocks 0..4095) + vpack (blocks 4096..5119) ----------
__global__ __launch_bounds__(256) void k_post(const u16* __restrict__ qh, const u16* __restrict__ kh,
                                              u16* __restrict__ QP, u16* __restrict__ KP,
                                              const u16* __restrict__ vh, u16* __restrict__ VP) {
  int bid = blockIdx.x;
  int tid = threadIdx.x;
  if (bid < 4096) {
    int l = tid & 63, wvv = tid >> 6;
    int rsub = l >> 4, c = l & 15;
    int row = bid * 16 + wvv * 4 + rsub;   // bh*2048 + s
    int bh = row >> 11, s = row & 2047;
    int tile = s >> 5, ln = s & 31;
    int ks = c >> 1, hi = c & 1;
    int k3 = ks & 3;
    const u16* qi = qh + (size_t)row * HD + 32 * k3 + 16 * hi;
    const u16* ki = kh + (size_t)row * HD + 32 * k3 + 16 * hi;
    float sn[8], cs[8];
    #pragma unroll
    for (int j = 0; j < 8; ++j) {
      int de = 16 * k3 + 8 * hi + j;
      float freq = exp2f((float)de * -0.20762050593046014f);  // theta^(-de/64)
      sincosf((float)s * freq, &sn[j], &cs[j]);
    }
    size_t off = ((((size_t)(bh * 64 + tile)) * 8 + ks) * 64 + hi * 32 + ln) * 8;
    {
      short8 a = *(const short8*)(qi);
      short8 b2 = *(const short8*)(qi + 8);
      u16x4 o0, o1;
      #pragma unroll
      for (int j = 0; j < 4; ++j) {
        float x0 = bf2f((u16)a[2 * j]), x1 = bf2f((u16)a[2 * j + 1]);
        o0[j] = f2bf((j & 1) ? (sn[j] * x0 + cs[j] * x1) : (cs[j] * x0 - sn[j] * x1));
      }
      #pragma unroll
      for (int j = 0; j < 4; ++j) {
        int jj = j + 4;
        float x0 = bf2f((u16)b2[2 * j]), x1 = bf2f((u16)b2[2 * j + 1]);
        o1[j] = f2bf((jj & 1) ? (sn[jj] * x0 + cs[jj] * x1) : (cs[jj] * x0 - sn[jj] * x1));
      }
      *(u16x4*)(QP + off) = o0; *(u16x4*)(QP + off + 4) = o1;
    }
    {
      short8 a = *(const short8*)(ki);
      short8 b2 = *(const short8*)(ki + 8);
      u16x4 o0, o1;
      #pragma unroll
      for (int j = 0; j < 4; ++j) {
        float x0 = bf2f((u16)a[2 * j]), x1 = bf2f((u16)a[2 * j + 1]);
        o0[j] = f2bf((j & 1) ? (sn[j] * x0 + cs[j] * x1) : (cs[j] * x0 - sn[j] * x1));
      }
      #pragma unroll
      for (int j = 0; j < 4; ++j) {
        int jj = j + 4;
        float x0 = bf2f((u16)b2[2 * j]), x1 = bf2f((u16)b2[2 * j + 1]);
        o1[j] = f2bf((jj & 1) ? (sn[jj] * x0 + cs[jj] * x1) : (cs[jj] * x0 - sn[jj] * x1));
      }
      *(u16x4*)(KP + off) = o0; *(u16x4*)(KP + off + 4) = o1;
    }
  } else {
    int c = bid - 4096;           // 0..1023
    int bx = c & 31;              // s-tile of 64
    int bh = c >> 5;
    __shared__ u16 t[64][136];
    int row = tid >> 2;
    int d0 = (tid & 3) * 32;
    const u16* src = vh + ((size_t)bh * S_LEN + bx * 64 + row) * HD + d0;
    short8 a = *(const short8*)(src);
    short8 b = *(const short8*)(src + 8);
    short8 cc2 = *(const short8*)(src + 16);
    short8 d = *(const short8*)(src + 24);
    *(short8*)(&t[row][d0]) = a;
    *(short8*)(&t[row][d0 + 8]) = b;
    *(short8*)(&t[row][d0 + 16]) = cc2;
    *(short8*)(&t[row][d0 + 24]) = d;
    __syncthreads();
    #pragma unroll
    for (int i = 0; i < 4; ++i) {
      int cid = i * 256 + tid;        // chunk id 0..1023
      int lp = cid & 63;
      int db = (cid >> 6) & 3;
      int j2 = (cid >> 8) & 1;
      int tl = (cid >> 9) & 1;
      int tg = bx * 2 + tl;
      int tloc = tl * 32 + j2 * 16 + (lp >> 5) * 8;
      int dloc = db * 32 + (lp & 31);
      short8 v;
      #pragma unroll
      for (int jj = 0; jj < 8; ++jj) v[jj] = (short)t[tloc + jj][dloc];
      size_t off = ((((size_t)(bh * 64 + tg) * 2 + j2) * 4 + db) * 64 + lp) * 8;
      *(short8*)(VP + off) = v;
    }
  }
}

// ---------- pipelined QKV GEMM: C[4096][6144] = A[4096][2048] * BT[6144][2048] ----------
// BM=128, BN=256, 8 waves (2x4), per-wave 64x64. K regions of 32, 3-slot LDS ring (72 KB
// -> 2 blocks/CU), counted vmcnt(3) (tail 0), one raw s_barrier per phase.
// Swizzle: chunk ^= (row>>1)&3 (2-way max = free). Head-major bf16 output.
__global__ __launch_bounds__(512, 2) void k_gemm_qkv2(const u16* __restrict__ A, const u16* __restrict__ BT,
                                                      const float* __restrict__ bq, const float* __restrict__ bk,
                                                      const float* __restrict__ bv, u16* __restrict__ qkv) {
  extern __shared__ __align__(16) char smraw[];
  u16* sm = (u16*)smraw;     // 3 slots x 12288 u16 (A:4096 + B:8192)
  int bid = blockIdx.x;      // 768 blocks
  int xcd = bid & 7, loc = bid >> 3;
  int bx = xcd * 3 + loc % 3;     // 0..23 (N-block of 256)
  int by = loc / 3;               // 0..31 (M-block of 128)
  int tid = threadIdx.x;
  int w = tid >> 6, lane = tid & 63;
  int wr = w >> 2, wc = w & 3;    // 2 x 4 waves
  int lq = lane & 15, lg = lane >> 4;

  f32x4 acc[4][4];
  #pragma unroll
  for (int mi = 0; mi < 4; ++mi)
    #pragma unroll
    for (int ni = 0; ni < 4; ++ni) acc[mi][ni] = (f32x4){0.f, 0.f, 0.f, 0.f};

  const size_t Abase = (size_t)(by * 128) * HID;
  const size_t Bbase = (size_t)(bx * 256) * HID;

  // stage region n (k = n*32 .. n*32+32) into slot n%3; source-side swizzle chunk^=(row>>1)&3
  #define STAGE_Q(n)  do { \
    int slot_ = ((n) % 3) * 12288; \
    int kb_ = (n) * 32; \
    { int c_ = tid; int row_ = c_ >> 2; int ch_ = (c_ & 3) ^ ((row_ >> 1) & 3); \
      gl_lds16(A + Abase + (size_t)row_ * HID + kb_ + ch_ * 8, sm + slot_ + c_ * 8); } \
    _Pragma("unroll") \
    for (int it_ = 0; it_ < 2; ++it_) { \
      int c_ = it_ * 512 + tid; int row_ = c_ >> 2; int ch_ = (c_ & 3) ^ ((row_ >> 1) & 3); \
      gl_lds16(BT + Bbase + (size_t)row_ * HID + kb_ + ch_ * 8, sm + slot_ + 4096 + c_ * 8); } \
  } while (0)

  STAGE_Q(0); STAGE_Q(1);
  asm volatile("s_waitcnt vmcnt(3)" ::: "memory");
  __builtin_amdgcn_s_barrier();
  __builtin_amdgcn_sched_barrier(0);

  for (int n = 0; n < 64; ++n) {
    if (n + 2 <= 63) STAGE_Q(n + 2);
    int slot = (n % 3) * 12288;
    const u16* sA = sm + slot;
    const u16* sB = sm + slot + 4096;
    short8 af[4], bf[4];
    #pragma unroll
    for (int mi = 0; mi < 4; ++mi) {
      int ra = wr * 64 + mi * 16 + lq;
      af[mi] = *(const short8*)(sA + ra * 32 + ((lg ^ ((ra >> 1) & 3)) << 3));
    }
    #pragma unroll
    for (int ni = 0; ni < 4; ++ni) {
      int rb = wc * 64 + ni * 16 + lq;
      bf[ni] = *(const short8*)(sB + rb * 32 + ((lg ^ ((rb >> 1) & 3)) << 3));
    }
    __builtin_amdgcn_s_setprio(1);
    #pragma unroll
    for (int mi = 0; mi < 4; ++mi)
      #pragma unroll
      for (int ni = 0; ni < 4; ++ni)
        acc[mi][ni] = __builtin_amdgcn_mfma_f32_16x16x32_bf16(af[mi], bf[ni], acc[mi][ni], 0, 0, 0);
    __builtin_amdgcn_s_setprio(0);
    if (n <= 61) {
      asm volatile("s_waitcnt vmcnt(3)" ::: "memory");
      __builtin_amdgcn_s_barrier();
      __builtin_amdgcn_sched_barrier(0);
    } else if (n == 62) {
      asm volatile("s_waitcnt vmcnt(0)" ::: "memory");
      __builtin_amdgcn_s_barrier();
      __builtin_amdgcn_sched_barrier(0);
    }
  }

  #pragma unroll
  for (int ni = 0; ni < 4; ++ni) {
    int colg = bx * 256 + wc * 64 + ni * 16 + lq;   // 0..6143
    int sel = colg >> 11;
    int col = colg & 2047;
    int h = col >> 7, d = col & 127;
    const float* bias = (sel == 0) ? bq : (sel == 1) ? bk : bv;
    float bs = bias[col];
    u16* outp = qkv + (size_t)sel * NROWS * HID;
    #pragma unroll
    for (int mi = 0; mi < 4; ++mi) {
      #pragma unroll
      for (int r = 0; r < 4; ++r) {
        int rowm = by * 128 + wr * 64 + mi * 16 + lg * 4 + r;
        int b = rowm >> 11, s = rowm & 2047;
        outp[(((size_t)(b * NH + h)) * S_LEN + s) * HD + d] = f2bf(acc[mi][ni][r] + bs);
      }
    }
  }
  #undef STAGE_Q
}

// ---------- pipelined output GEMM: C[4096][2048] f32 = A*BT + bias + resid ----------
// BM=BN=128, 4 waves (2x2), 3-slot 48 KB ring -> 3 blocks/CU; grid 512 (2/CU co-resident).
__global__ __launch_bounds__(256, 3) void k_gemm_o2(const u16* __restrict__ A, const u16* __restrict__ BT,
                                                    const float* __restrict__ bias,
                                                    const float* __restrict__ resid,
                                                    float* __restrict__ outp) {
  extern __shared__ __align__(16) char smraw[];
  u16* sm = (u16*)smraw;     // 3 slots x 8192 u16 (A:4096 + B:4096)
  int bid = blockIdx.x;      // 512 blocks
  int xcd = bid & 7, loc = bid >> 3;   // loc 0..63
  int bx = xcd * 2 + (loc & 1);  // 0..15 (N-block of 128)
  int by = loc >> 1;             // 0..31
  int tid = threadIdx.x;
  int w = tid >> 6, lane = tid & 63;
  int wr = w >> 1, wc = w & 1;
  int lq = lane & 15, lg = lane >> 4;

  f32x4 acc[4][4];
  #pragma unroll
  for (int mi = 0; mi < 4; ++mi)
    #pragma unroll
    for (int ni = 0; ni < 4; ++ni) acc[mi][ni] = (f32x4){0.f, 0.f, 0.f, 0.f};

  const size_t Abase = (size_t)(by * 128) * HID;
  const size_t Bbase = (size_t)(bx * 128) * HID;

  #define STAGE_O(n)  do { \
    int slot_ = ((n) % 3) * 8192; \
    int kb_ = (n) * 32; \
    _Pragma("unroll") \
    for (int it_ = 0; it_ < 2; ++it_) { \
      int c_ = it_ * 256 + tid; int row_ = c_ >> 2; int ch_ = (c_ & 3) ^ ((row_ >> 1) & 3); \
      gl_lds16(A + Abase + (size_t)row_ * HID + kb_ + ch_ * 8, sm + slot_ + c_ * 8); } \
    _Pragma("unroll") \
    for (int it_ = 0; it_ < 2; ++it_) { \
      int c_ = it_ * 256 + tid; int row_ = c_ >> 2; int ch_ = (c_ & 3) ^ ((row_ >> 1) & 3); \
      gl_lds16(BT + Bbase + (size_t)row_ * HID + kb_ + ch_ * 8, sm + slot_ + 4096 + c_ * 8); } \
  } while (0)

  STAGE_O(0); STAGE_O(1);
  asm volatile("s_waitcnt vmcnt(4)" ::: "memory");
  __builtin_amdgcn_s_barrier();
  __builtin_amdgcn_sched_barrier(0);

  for (int n = 0; n < 64; ++n) {
    if (n + 2 <= 63) STAGE_O(n + 2);
    int slot = (n % 3) * 8192;
    const u16* sA = sm + slot;
    const u16* sB = sm + slot + 4096;
    short8 af[4], bf[4];
    #pragma unroll
    for (int mi = 0; mi < 4; ++mi) {
      int ra = wr * 64 + mi * 16 + lq;
      af[mi] = *(const short8*)(sA + ra * 32 + ((lg ^ ((ra >> 1) & 3)) << 3));
    }
    #pragma unroll
    for (int ni = 0; ni < 4; ++ni) {
      int rb = wc * 64 + ni * 16 + lq;
      bf[ni] = *(const short8*)(sB + rb * 32 + ((lg ^ ((rb >> 1) & 3)) << 3));
    }
    __builtin_amdgcn_s_setprio(1);
    #pragma unroll
    for (int mi = 0; mi < 4; ++mi)
      #pragma unroll
      for (int ni = 0; ni < 4; ++ni)
        acc[mi][ni] = __builtin_amdgcn_mfma_f32_16x16x32_bf16(af[mi], bf[ni], acc[mi][ni], 0, 0, 0);
    __builtin_amdgcn_s_setprio(0);
    if (n <= 61) {
      asm volatile("s_waitcnt vmcnt(4)" ::: "memory");
      __builtin_amdgcn_s_barrier();
      __builtin_amdgcn_sched_barrier(0);
    } else if (n == 62) {
      asm volatile("s_waitcnt vmcnt(0)" ::: "memory");
      __builtin_amdgcn_s_barrier();
      __builtin_amdgcn_sched_barrier(0);
    }
  }

  #pragma unroll
  for (int ni = 0; ni < 4; ++ni) {
    int col = bx * 128 + wc * 64 + ni * 16 + lq;
    float bs = bias[col];
    #pragma unroll
    for (int mi = 0; mi < 4; ++mi) {
      #pragma unroll
      for (int r = 0; r < 4; ++r) {
        int rowm = by * 128 + wr * 64 + mi * 16 + lg * 4 + r;
        size_t o = (size_t)rowm * HID + col;
        outp[o] = acc[mi][ni][r] + bs + resid[o];
      }
    }
  }
  #undef STAGE_O
}

// ---------- flash attention v6: barrier-free, LDS-free, packed fragment loads ----------
// QP,KP: [bh][tile][ks(8)][lane][8]; VP: [bh][tile][j2(2)][db(4)][lane][8]; out bf16 [b][s][h*128+d]
__global__ __launch_bounds__(64, 2) void k_attn(const u16* __restrict__ QP, const u16* __restrict__ KP,
                                                const u16* __restrict__ VP, u16* __restrict__ out) {
  int bid = blockIdx.x;            // 2048 one-wave blocks
  int rest = bid >> 3;
  int bh = (bid & 7) * 4 + (rest & 3);   // 4 heads per XCD
  int gg = rest >> 2;                    // 0..63
  int qw = (gg < 32) ? (63 - gg) : (gg - 32);  // complement-paired for balance
  int b = bh >> 4, h = bh & 15;
  int lane = threadIdx.x;
  int hi = lane >> 5, ln = lane & 31;
  int q0 = qw * 32, qrow = q0 + ln;

  const u16* QPb = QP + ((size_t)(bh * 64 + qw) * 8) * 512 + lane * 8;
  short8 qf[8];
  #pragma unroll
  for (int ks = 0; ks < 8; ++ks) qf[ks] = *(const short8*)(QPb + ks * 512);

  f32x16 oc[4];
  #pragma unroll
  for (int db = 0; db < 4; ++db)
    #pragma unroll
    for (int r = 0; r < 16; ++r) oc[db][r] = 0.f;
  float mr = -3.0e38f, l = 0.f;

  const u16* KPb = KP + ((size_t)bh * 64 * 8) * 512 + lane * 8;  // + tt*4096 + ks*512
  const u16* VPb = VP + ((size_t)bh * 64 * 8) * 512 + lane * 8;  // + tt*4096 + (j2*4+db)*512

  int ntile = qw + 1;
  short8 kf[8];
  #pragma unroll
  for (int ks = 0; ks < 8; ++ks) kf[ks] = *(const short8*)(KPb + ks * 512);  // tile 0

  for (int tt = 0; tt < ntile; ++tt) {
    // V fragments for this tile (consumed after softmax — latency hidden)
    short8 va[8];
    #pragma unroll
    for (int u = 0; u < 8; ++u) va[u] = *(const short8*)(VPb + (size_t)tt * 4096 + u * 512);

    // S^T = K · Q
    f32x16 st;
    #pragma unroll
    for (int r = 0; r < 16; ++r) st[r] = 0.f;
    __builtin_amdgcn_s_setprio(1);
    #pragma unroll
    for (int ks = 0; ks < 8; ++ks)
      st = __builtin_amdgcn_mfma_f32_32x32x16_bf16(kf[ks], qf[ks], st, 0, 0, 0);
    __builtin_amdgcn_s_setprio(0);

    // prefetch next K tile (lands during softmax + PV)
    if (tt + 1 < ntile) {
      #pragma unroll
      for (int ks = 0; ks < 8; ++ks)
        kf[ks] = *(const short8*)(KPb + (size_t)(tt + 1) * 4096 + ks * 512);
    }

    int t0 = tt * 32;
    float sv[16];
    float pm = -3.0e38f;
    bool lastt = (tt == ntile - 1);
    #pragma unroll
    for (int r = 0; r < 16; ++r) {
      float x = st[r];
      if (lastt) {
        int t = t0 + (r & 3) + 8 * (r >> 2) + 4 * hi;
        x = (t <= qrow) ? x : -3.0e38f;
      }
      sv[r] = x;
    }
    #pragma unroll
    for (int r = 0; r < 15; r += 2) pm = fmaxf(fmaxf(pm, sv[r]), sv[r + 1]);
    pm = fmaxf(pm, sv[15]);
    pm = fmaxf(pm, __shfl_xor(pm, 32, 64));
    if (!__all(pm <= mr + 64.0f)) {
      float mnew = fmaxf(mr, pm);
      float al = exp2f((mr - mnew) * C2);
      l *= al;
      #pragma unroll
      for (int db = 0; db < 4; ++db)
        #pragma unroll
        for (int r = 0; r < 16; ++r) oc[db][r] *= al;
      mr = mnew;
    }
    float mc = mr * C2;
    float e[16];
    float rs = 0.f;
    #pragma unroll
    for (int r = 0; r < 16; ++r) {
      e[r] = exp2f(fmaf(sv[r], C2, -mc));
      rs += e[r];
    }
    rs += __shfl_xor(rs, 32, 64);
    l += rs;

    // P -> bf16 B-frags in-register (cvt_pk + permlane32_swap)
    unsigned w0 = cvtpk(e[0], e[1]),   w1 = cvtpk(e[2], e[3]);
    unsigned w2 = cvtpk(e[4], e[5]),   w3 = cvtpk(e[6], e[7]);
    unsigned w4 = cvtpk(e[8], e[9]),   w5 = cvtpk(e[10], e[11]);
    unsigned w6 = cvtpk(e[12], e[13]), w7 = cvtpk(e[14], e[15]);
    plswap(w0, w2); plswap(w1, w3); plswap(w4, w6); plswap(w5, w7);
    u32x4 pw0 = {w0, w1, w2, w3};
    u32x4 pw1 = {w4, w5, w6, w7};
    short8 pb0 = __builtin_bit_cast(short8, pw0);
    short8 pb1 = __builtin_bit_cast(short8, pw1);

    // O^T += V^T · P
    __builtin_amdgcn_s_setprio(1);
    #pragma unroll
    for (int db = 0; db < 4; ++db)
      oc[db] = __builtin_amdgcn_mfma_f32_32x32x16_bf16(va[db], pb0, oc[db], 0, 0, 0);
    #pragma unroll
    for (int db = 0; db < 4; ++db)
      oc[db] = __builtin_amdgcn_mfma_f32_32x32x16_bf16(va[4 + db], pb1, oc[db], 0, 0, 0);
    __builtin_amdgcn_s_setprio(0);
  }

  // epilogue: out[b][s=qrow][h*128 + d], d = db*32 + 8g + 4hi + j
  float inv = 1.0f / l;
  size_t ob = ((size_t)(b * S_LEN + qrow)) * HID + h * HD;
  #pragma unroll
  for (int db = 0; db < 4; ++db) {
    #pragma unroll
    for (int g = 0; g < 4; ++g) {
      u16x4 pk;
      #pragma unroll
      for (int j = 0; j < 4; ++j) pk[j] = f2bf(oc[db][4 * g + j] * inv);
      *(u16x4*)(out + ob + db * 32 + 8 * g + 4 * hi) = pk;
    }
  }
}

extern "C" void kernel_launch(void* const* d_in, const int* in_sizes, int n_in,
                              void* d_out, int out_size, void* d_ws, size_t ws_size,
                              hipStream_t stream) {
  const float* x    = (const float*)d_in[0];
  const float* rmsw = (const float*)d_in[1];
  const float* wq   = (const float*)d_in[2];
  const float* bq   = (const float*)d_in[3];
  const float* wk   = (const float*)d_in[4];
  const float* bk   = (const float*)d_in[5];
  const float* wv   = (const float*)d_in[6];
  const float* bv   = (const float*)d_in[7];
  const float* wo   = (const float*)d_in[8];
  const float* bo   = (const float*)d_in[9];

  char* ws = (char*)d_ws;
  const size_t SZ = (size_t)NROWS * HID * 2;  // 16 MB bf16 activation
  const size_t WSZ = (size_t)HID * HID * 2;   // 8 MB bf16 weight
  u16* xn   = (u16*)(ws);                     // 0-16 MB;  reused as QP
  u16* wqkT = (u16*)(ws + SZ);                // 16-40 MB; first 16 MB reused as KP
  u16* woT  = (u16*)(ws + SZ + 3 * WSZ);      // 40-48 MB, live till end
  u16* qhm  = (u16*)(ws + SZ + 4 * WSZ);      // 48-64 MB; reused as ao
  u16* khm  = (u16*)(ws + SZ + 4 * WSZ + SZ); // 64-80 MB; reused as VP
  u16* vhm  = (u16*)(ws + SZ + 4 * WSZ + 2 * SZ);  // 80-96 MB
  u16* QP   = xn;
  u16* KP   = wqkT;
  u16* VP   = khm;   // khm dead after ropepack
  u16* ao   = qhm;   // qhm dead after ropepack

  k_pre<<<dim3(8192), dim3(256), 0, stream>>>(x, rmsw, xn, wq, wk, wv, wo, wqkT);
  k_gemm_qkv2<<<dim3(768), dim3(512), 73728, stream>>>(xn, wqkT, bq, bk, bv, qhm);
  k_post<<<dim3(5120), dim3(256), 0, stream>>>(qhm, khm, QP, KP, vhm, VP);
  k_attn<<<dim3(2048), dim3(64), 0, stream>>>(QP, KP, VP, ao);
  k_gemm_o2<<<dim3(512), dim3(256), 49152, stream>>>(ao, woT, bo, x, (float*)d_out);
}

// Round 18
// 255.221 us; speedup vs baseline: 1.0430x; 1.0328x over previous
//
#include <hip/hip_runtime.h>
#include <stdint.h>
#include <math.h>

#define S_LEN 2048
#define HID 2048
#define NH 16
#define HD 128
#define NROWS 4096  // B*S
#define SCALE 0.08838834764831845f
#define C2 (0.08838834764831845f * 1.442695040888963f)  // SCALE * log2(e)

typedef unsigned short u16;
typedef __attribute__((ext_vector_type(8))) short short8;
typedef __attribute__((ext_vector_type(4))) float f32x4;
typedef __attribute__((ext_vector_type(16))) float f32x16;
typedef __attribute__((ext_vector_type(4))) unsigned short u16x4;
typedef __attribute__((ext_vector_type(4))) unsigned int u32x4;
typedef __attribute__((ext_vector_type(4))) float float4v;

__device__ __forceinline__ u16 f2bf(float f) {
  union { float f; uint32_t u; } v; v.f = f;
  uint32_t r = v.u + 0x7FFFu + ((v.u >> 16) & 1u);
  return (u16)(r >> 16);
}
__device__ __forceinline__ float bf2f(u16 b) {
  union { uint32_t u; float f; } v; v.u = ((uint32_t)b) << 16;
  return v.f;
}
__device__ __forceinline__ void gl_lds16(const void* g, void* l) {
  __builtin_amdgcn_global_load_lds((const __attribute__((address_space(1))) void*)g,
                                   (__attribute__((address_space(3))) void*)l, 16, 0, 0);
}
__device__ __forceinline__ unsigned cvtpk(float lo, float hi) {
  unsigned r;
  asm("v_cvt_pk_bf16_f32 %0, %1, %2" : "=v"(r) : "v"(lo), "v"(hi));
  return r;
}
__device__ __forceinline__ void plswap(unsigned &a, unsigned &b) {
  asm volatile("v_permlane32_swap_b32 %0, %1" : "+v"(a), "+v"(b));
}

// ---------- merged pre-pass: rmsnorm (blocks 0..4095) + wconv4 (blocks 4096..8191) ----------
__global__ __launch_bounds__(256) void k_pre(const float* __restrict__ x, const float* __restrict__ rw,
                                             u16* __restrict__ xn,
                                             const float* __restrict__ w0, const float* __restrict__ w1,
                                             const float* __restrict__ w2, const float* __restrict__ w3,
                                             u16* __restrict__ wtbase) {
  int bid = blockIdx.x;
  int tid = threadIdx.x;
  if (bid < 4096) {
    int row = bid;
    const float* xr = x + (size_t)row * HID;
    float4v a = *(const float4v*)(xr + tid * 8);
    float4v b = *(const float4v*)(xr + tid * 8 + 4);
    float s = a[0]*a[0] + a[1]*a[1] + a[2]*a[2] + a[3]*a[3]
            + b[0]*b[0] + b[1]*b[1] + b[2]*b[2] + b[3]*b[3];
    #pragma unroll
    for (int off = 1; off < 64; off <<= 1) s += __shfl_xor(s, off, 64);
    __shared__ float red[4];
    int wv = tid >> 6;
    if ((tid & 63) == 0) red[wv] = s;
    __syncthreads();
    float tot = red[0] + red[1] + red[2] + red[3];
    float r = rsqrtf(tot * (1.0f / HID) + 1e-5f);
    const float* wp = rw + tid * 8;
    u16x4 o0, o1;
    #pragma unroll
    for (int j = 0; j < 4; ++j) { o0[j] = f2bf(a[j] * r * wp[j]); o1[j] = f2bf(b[j] * r * wp[4 + j]); }
    *(u16x4*)(xn + (size_t)row * HID + tid * 8) = o0;
    *(u16x4*)(xn + (size_t)row * HID + tid * 8 + 4) = o1;
  } else {
    int c = bid - 4096;
    int z = c >> 10;
    int rest = c & 1023;
    int n0 = (rest & 31) * 64, k0 = (rest >> 5) * 64;
    const float* w = (z == 0) ? w0 : (z == 1) ? w1 : (z == 2) ? w2 : w3;
    u16* wt = wtbase + (size_t)z * HID * HID;
    __shared__ float t[64][68];
    int cr = tid >> 4;
    int cc = (tid & 15) * 4;
    #pragma unroll
    for (int it = 0; it < 4; ++it) {
      int kk = cr + it * 16;
      float4v v = *(const float4v*)(w + (size_t)(k0 + kk) * HID + n0 + cc);
      t[kk][cc] = v[0]; t[kk][cc + 1] = v[1]; t[kk][cc + 2] = v[2]; t[kk][cc + 3] = v[3];
    }
    __syncthreads();
    #pragma unroll
    for (int it = 0; it < 4; ++it) {
      int nn = cr + it * 16;
      u16x4 o;
      #pragma unroll
      for (int j = 0; j < 4; ++j) o[j] = f2bf(t[cc + j][nn]);
      *(u16x4*)(wt + (size_t)(n0 + nn) * HID + k0 + cc) = o;
    }
  }
}

// ---------- merged post-pass: ropepack (blocks 0..4095) + vpack (blocks 4096..5119) ----------
__global__ __launch_bounds__(256) void k_post(const u16* __restrict__ qh, const u16* __restrict__ kh,
                                              u16* __restrict__ QP, u16* __restrict__ KP,
                                              const u16* __restrict__ vh, u16* __restrict__ VP) {
  int bid = blockIdx.x;
  int tid = threadIdx.x;
  if (bid < 4096) {
    int l = tid & 63, wvv = tid >> 6;
    int rsub = l >> 4, c = l & 15;
    int row = bid * 16 + wvv * 4 + rsub;   // bh*2048 + s
    int bh = row >> 11, s = row & 2047;
    int tile = s >> 5, ln = s & 31;
    int ks = c >> 1, hi = c & 1;
    int k3 = ks & 3;
    const u16* qi = qh + (size_t)row * HD + 32 * k3 + 16 * hi;
    const u16* ki = kh + (size_t)row * HD + 32 * k3 + 16 * hi;
    float sn[8], cs[8];
    #pragma unroll
    for (int j = 0; j < 8; ++j) {
      int de = 16 * k3 + 8 * hi + j;
      float freq = exp2f((float)de * -0.20762050593046014f);  // theta^(-de/64)
      sincosf((float)s * freq, &sn[j], &cs[j]);
    }
    size_t off = ((((size_t)(bh * 64 + tile)) * 8 + ks) * 64 + hi * 32 + ln) * 8;
    {
      short8 a = *(const short8*)(qi);
      short8 b2 = *(const short8*)(qi + 8);
      u16x4 o0, o1;
      #pragma unroll
      for (int j = 0; j < 4; ++j) {
        float x0 = bf2f((u16)a[2 * j]), x1 = bf2f((u16)a[2 * j + 1]);
        o0[j] = f2bf((j & 1) ? (sn[j] * x0 + cs[j] * x1) : (cs[j] * x0 - sn[j] * x1));
      }
      #pragma unroll
      for (int j = 0; j < 4; ++j) {
        int jj = j + 4;
        float x0 = bf2f((u16)b2[2 * j]), x1 = bf2f((u16)b2[2 * j + 1]);
        o1[j] = f2bf((jj & 1) ? (sn[jj] * x0 + cs[jj] * x1) : (cs[jj] * x0 - sn[jj] * x1));
      }
      *(u16x4*)(QP + off) = o0; *(u16x4*)(QP + off + 4) = o1;
    }
    {
      short8 a = *(const short8*)(ki);
      short8 b2 = *(const short8*)(ki + 8);
      u16x4 o0, o1;
      #pragma unroll
      for (int j = 0; j < 4; ++j) {
        float x0 = bf2f((u16)a[2 * j]), x1 = bf2f((u16)a[2 * j + 1]);
        o0[j] = f2bf((j & 1) ? (sn[j] * x0 + cs[j] * x1) : (cs[j] * x0 - sn[j] * x1));
      }
      #pragma unroll
      for (int j = 0; j < 4; ++j) {
        int jj = j + 4;
        float x0 = bf2f((u16)b2[2 * j]), x1 = bf2f((u16)b2[2 * j + 1]);
        o1[j] = f2bf((jj & 1) ? (sn[jj] * x0 + cs[jj] * x1) : (cs[jj] * x0 - sn[jj] * x1));
      }
      *(u16x4*)(KP + off) = o0; *(u16x4*)(KP + off + 4) = o1;
    }
  } else {
    int c = bid - 4096;           // 0..1023
    int bx = c & 31;              // s-tile of 64
    int bh = c >> 5;
    __shared__ u16 t[64][136];
    int row = tid >> 2;
    int d0 = (tid & 3) * 32;
    const u16* src = vh + ((size_t)bh * S_LEN + bx * 64 + row) * HD + d0;
    short8 a = *(const short8*)(src);
    short8 b = *(const short8*)(src + 8);
    short8 cc2 = *(const short8*)(src + 16);
    short8 d = *(const short8*)(src + 24);
    *(short8*)(&t[row][d0]) = a;
    *(short8*)(&t[row][d0 + 8]) = b;
    *(short8*)(&t[row][d0 + 16]) = cc2;
    *(short8*)(&t[row][d0 + 24]) = d;
    __syncthreads();
    #pragma unroll
    for (int i = 0; i < 4; ++i) {
      int cid = i * 256 + tid;        // chunk id 0..1023
      int lp = cid & 63;
      int db = (cid >> 6) & 3;
      int j2 = (cid >> 8) & 1;
      int tl = (cid >> 9) & 1;
      int tg = bx * 2 + tl;
      int tloc = tl * 32 + j2 * 16 + (lp >> 5) * 8;
      int dloc = db * 32 + (lp & 31);
      short8 v;
      #pragma unroll
      for (int jj = 0; jj < 8; ++jj) v[jj] = (short)t[tloc + jj][dloc];
      size_t off = ((((size_t)(bh * 64 + tg) * 2 + j2) * 4 + db) * 64 + lp) * 8;
      *(short8*)(VP + off) = v;
    }
  }
}

// ---------- deep-pipelined QKV GEMM: C[4096][6144] = A[4096][2048] * BT[6144][2048] ----------
// BM=128, BN=256, 8 waves (2x4), per-wave 64x64, BK=64. 3-slot LDS ring of 48 KB K-tiles
// (144 KB -> 1 block/CU). Per K-tile: 2 phases x 16 MFMA (A-frags hoisted in q0).
// Stage t+2 per phase (q0: A+B0, q1: B1); vmcnt(6) at even-phase tops (vmcnt(0) at t=31).
// Swizzle: chunk ^= row&7 (involution; 2-way banks = free). Head-major bf16 output.
__global__ __launch_bounds__(512, 1) void k_gemm_qkv2(const u16* __restrict__ A, const u16* __restrict__ BT,
                                                      const float* __restrict__ bq, const float* __restrict__ bk,
                                                      const float* __restrict__ bv, u16* __restrict__ qkv) {
  extern __shared__ __align__(16) char smraw[];
  u16* sm = (u16*)smraw;     // 3 slots x 24576 u16 (A:[128][64]=8192 + B:[256][64]=16384)
  int bid = blockIdx.x;      // 768 blocks
  int xcd = bid & 7, loc = bid >> 3;
  int bx = xcd * 3 + loc % 3;     // 0..23 (N-block of 256)
  int by = loc / 3;               // 0..31 (M-block of 128)
  int tid = threadIdx.x;
  int w = tid >> 6, lane = tid & 63;
  int wr = w >> 2, wc = w & 3;    // 2 x 4 waves
  int lq = lane & 15, lg = lane >> 4;

  f32x4 acc[4][4];
  #pragma unroll
  for (int mi = 0; mi < 4; ++mi)
    #pragma unroll
    for (int ni = 0; ni < 4; ++ni) acc[mi][ni] = (f32x4){0.f, 0.f, 0.f, 0.f};

  const size_t Abase = (size_t)(by * 128) * HID;
  const size_t Bbase = (size_t)(bx * 256) * HID;

  // A-tile of K-tile n: 128x64, 1024 16B-chunks, 2 instr/thread
  #define STAGE_A(n)  do { \
    int slot_ = ((n) % 3) * 24576; \
    int kb_ = (n) * 64; \
    _Pragma("unroll") \
    for (int it_ = 0; it_ < 2; ++it_) { \
      int c_ = it_ * 512 + tid; int row_ = c_ >> 3; int cs_ = (c_ & 7) ^ (row_ & 7); \
      gl_lds16(A + Abase + (size_t)row_ * HID + kb_ + cs_ * 8, sm + slot_ + c_ * 8); } \
  } while (0)
  // B half h (rows 128h..128h+127 of the 256-row tile): 2 instr/thread
  #define STAGE_B(n, h)  do { \
    int slot_ = ((n) % 3) * 24576; \
    int kb_ = (n) * 64; \
    _Pragma("unroll") \
    for (int it_ = 0; it_ < 2; ++it_) { \
      int c_ = it_ * 512 + tid; int row_ = c_ >> 3; int cs_ = (c_ & 7) ^ (row_ & 7); \
      gl_lds16(BT + Bbase + (size_t)(128 * (h) + row_) * HID + kb_ + cs_ * 8, \
               sm + slot_ + 8192 + 8192 * (h) + c_ * 8); } \
  } while (0)

  // prologue: tiles 0 and 1 (12 instr); ring stages tile t+2 during tile t
  STAGE_A(0); STAGE_B(0, 0); STAGE_B(0, 1);
  STAGE_A(1); STAGE_B(1, 0); STAGE_B(1, 1);
  asm volatile("s_waitcnt vmcnt(6)" ::: "memory");   // tile 0 landed
  __builtin_amdgcn_s_barrier();
  __builtin_amdgcn_sched_barrier(0);

  for (int t = 0; t < 32; ++t) {
    int slot = (t % 3) * 24576;
    const u16* sA = sm + slot;
    const u16* sB = sm + slot + 8192;   // [256][64]
    // ---- phase q0: read af (8) + bf ni 0,1 (4); stage A(t+2)+B0(t+2); MFMA ni 0,1 ----
    if (t == 31) asm volatile("s_waitcnt vmcnt(0)" ::: "memory");
    else         asm volatile("s_waitcnt vmcnt(6)" ::: "memory");
    short8 af[4][2], bf0[2][2];
    #pragma unroll
    for (int mi = 0; mi < 4; ++mi) {
      int ra = wr * 64 + mi * 16 + lq;
      #pragma unroll
      for (int ks = 0; ks < 2; ++ks)
        af[mi][ks] = *(const short8*)(sA + ra * 64 + (((ks * 4 + lg) ^ (ra & 7)) << 3));
    }
    #pragma unroll
    for (int nl = 0; nl < 2; ++nl) {
      int rb = wc * 64 + nl * 16 + lq;
      #pragma unroll
      for (int ks = 0; ks < 2; ++ks)
        bf0[nl][ks] = *(const short8*)(sB + rb * 64 + (((ks * 4 + lg) ^ (rb & 7)) << 3));
    }
    if (t + 2 < 32) { STAGE_A(t + 2); STAGE_B(t + 2, 0); }
    __builtin_amdgcn_s_setprio(1);
    #pragma unroll
    for (int ks = 0; ks < 2; ++ks)
      #pragma unroll
      for (int mi = 0; mi < 4; ++mi)
        #pragma unroll
        for (int nl = 0; nl < 2; ++nl)
          acc[mi][nl] = __builtin_amdgcn_mfma_f32_16x16x32_bf16(af[mi][ks], bf0[nl][ks], acc[mi][nl], 0, 0, 0);
    __builtin_amdgcn_s_setprio(0);
    __builtin_amdgcn_s_barrier();
    __builtin_amdgcn_sched_barrier(0);
    // ---- phase q1: read bf ni 2,3 (4); stage B1(t+2); MFMA ni 2,3 (af reused) ----
    short8 bf1[2][2];
    #pragma unroll
    for (int nl = 0; nl < 2; ++nl) {
      int rb = wc * 64 + (nl + 2) * 16 + lq;
      #pragma unroll
      for (int ks = 0; ks < 2; ++ks)
        bf1[nl][ks] = *(const short8*)(sB + rb * 64 + (((ks * 4 + lg) ^ (rb & 7)) << 3));
    }
    if (t + 2 < 32) STAGE_B(t + 2, 1);
    __builtin_amdgcn_s_setprio(1);
    #pragma unroll
    for (int ks = 0; ks < 2; ++ks)
      #pragma unroll
      for (int mi = 0; mi < 4; ++mi)
        #pragma unroll
        for (int nl = 0; nl < 2; ++nl)
          acc[mi][nl + 2] = __builtin_amdgcn_mfma_f32_16x16x32_bf16(af[mi][ks], bf1[nl][ks], acc[mi][nl + 2], 0, 0, 0);
    __builtin_amdgcn_s_setprio(0);
    __builtin_amdgcn_s_barrier();
    __builtin_amdgcn_sched_barrier(0);
  }

  #pragma unroll
  for (int ni = 0; ni < 4; ++ni) {
    int colg = bx * 256 + wc * 64 + ni * 16 + lq;   // 0..6143
    int sel = colg >> 11;
    int col = colg & 2047;
    int h = col >> 7, d = col & 127;
    const float* bias = (sel == 0) ? bq : (sel == 1) ? bk : bv;
    float bs = bias[col];
    u16* outp = qkv + (size_t)sel * NROWS * HID;
    #pragma unroll
    for (int mi = 0; mi < 4; ++mi) {
      #pragma unroll
      for (int r = 0; r < 4; ++r) {
        int rowm = by * 128 + wr * 64 + mi * 16 + lg * 4 + r;
        int b = rowm >> 11, s = rowm & 2047;
        outp[(((size_t)(b * NH + h)) * S_LEN + s) * HD + d] = f2bf(acc[mi][ni][r] + bs);
      }
    }
  }
  #undef STAGE_A
  #undef STAGE_B
}

// ---------- pipelined output GEMM: C[4096][2048] f32 = A*BT + bias + resid ----------
// BM=BN=128, 4 waves (2x2), 3-slot 48 KB ring -> 3 blocks/CU; grid 512 (2/CU co-resident).
__global__ __launch_bounds__(256, 3) void k_gemm_o2(const u16* __restrict__ A, const u16* __restrict__ BT,
                                                    const float* __restrict__ bias,
                                                    const float* __restrict__ resid,
                                                    float* __restrict__ outp) {
  extern __shared__ __align__(16) char smraw[];
  u16* sm = (u16*)smraw;     // 3 slots x 8192 u16 (A:4096 + B:4096)
  int bid = blockIdx.x;      // 512 blocks
  int xcd = bid & 7, loc = bid >> 3;   // loc 0..63
  int bx = xcd * 2 + (loc & 1);  // 0..15 (N-block of 128)
  int by = loc >> 1;             // 0..31
  int tid = threadIdx.x;
  int w = tid >> 6, lane = tid & 63;
  int wr = w >> 1, wc = w & 1;
  int lq = lane & 15, lg = lane >> 4;

  f32x4 acc[4][4];
  #pragma unroll
  for (int mi = 0; mi < 4; ++mi)
    #pragma unroll
    for (int ni = 0; ni < 4; ++ni) acc[mi][ni] = (f32x4){0.f, 0.f, 0.f, 0.f};

  const size_t Abase = (size_t)(by * 128) * HID;
  const size_t Bbase = (size_t)(bx * 128) * HID;

  #define STAGE_O(n)  do { \
    int slot_ = ((n) % 3) * 8192; \
    int kb_ = (n) * 32; \
    _Pragma("unroll") \
    for (int it_ = 0; it_ < 2; ++it_) { \
      int c_ = it_ * 256 + tid; int row_ = c_ >> 2; int ch_ = (c_ & 3) ^ ((row_ >> 1) & 3); \
      gl_lds16(A + Abase + (size_t)row_ * HID + kb_ + ch_ * 8, sm + slot_ + c_ * 8); } \
    _Pragma("unroll") \
    for (int it_ = 0; it_ < 2; ++it_) { \
      int c_ = it_ * 256 + tid; int row_ = c_ >> 2; int ch_ = (c_ & 3) ^ ((row_ >> 1) & 3); \
      gl_lds16(BT + Bbase + (size_t)row_ * HID + kb_ + ch_ * 8, sm + slot_ + 4096 + c_ * 8); } \
  } while (0)

  STAGE_O(0); STAGE_O(1);
  asm volatile("s_waitcnt vmcnt(4)" ::: "memory");
  __builtin_amdgcn_s_barrier();
  __builtin_amdgcn_sched_barrier(0);

  for (int n = 0; n < 64; ++n) {
    if (n + 2 <= 63) STAGE_O(n + 2);
    int slot = (n % 3) * 8192;
    const u16* sA = sm + slot;
    const u16* sB = sm + slot + 4096;
    short8 af[4], bf[4];
    #pragma unroll
    for (int mi = 0; mi < 4; ++mi) {
      int ra = wr * 64 + mi * 16 + lq;
      af[mi] = *(const short8*)(sA + ra * 32 + ((lg ^ ((ra >> 1) & 3)) << 3));
    }
    #pragma unroll
    for (int ni = 0; ni < 4; ++ni) {
      int rb = wc * 64 + ni * 16 + lq;
      bf[ni] = *(const short8*)(sB + rb * 32 + ((lg ^ ((rb >> 1) & 3)) << 3));
    }
    __builtin_amdgcn_s_setprio(1);
    #pragma unroll
    for (int mi = 0; mi < 4; ++mi)
      #pragma unroll
      for (int ni = 0; ni < 4; ++ni)
        acc[mi][ni] = __builtin_amdgcn_mfma_f32_16x16x32_bf16(af[mi], bf[ni], acc[mi][ni], 0, 0, 0);
    __builtin_amdgcn_s_setprio(0);
    if (n <= 61) {
      asm volatile("s_waitcnt vmcnt(4)" ::: "memory");
      __builtin_amdgcn_s_barrier();
      __builtin_amdgcn_sched_barrier(0);
    } else if (n == 62) {
      asm volatile("s_waitcnt vmcnt(0)" ::: "memory");
      __builtin_amdgcn_s_barrier();
      __builtin_amdgcn_sched_barrier(0);
    }
  }

  #pragma unroll
  for (int ni = 0; ni < 4; ++ni) {
    int col = bx * 128 + wc * 64 + ni * 16 + lq;
    float bs = bias[col];
    #pragma unroll
    for (int mi = 0; mi < 4; ++mi) {
      #pragma unroll
      for (int r = 0; r < 4; ++r) {
        int rowm = by * 128 + wr * 64 + mi * 16 + lg * 4 + r;
        size_t o = (size_t)rowm * HID + col;
        outp[o] = acc[mi][ni][r] + bs + resid[o];
      }
    }
  }
  #undef STAGE_O
}

// ---------- flash attention v6: barrier-free, LDS-free, packed fragment loads ----------
// QP,KP: [bh][tile][ks(8)][lane][8]; VP: [bh][tile][j2(2)][db(4)][lane][8]; out bf16 [b][s][h*128+d]
__global__ __launch_bounds__(64, 2) void k_attn(const u16* __restrict__ QP, const u16* __restrict__ KP,
                                                const u16* __restrict__ VP, u16* __restrict__ out) {
  int bid = blockIdx.x;            // 2048 one-wave blocks
  int rest = bid >> 3;
  int bh = (bid & 7) * 4 + (rest & 3);   // 4 heads per XCD
  int gg = rest >> 2;                    // 0..63
  int qw = (gg < 32) ? (63 - gg) : (gg - 32);  // complement-paired for balance
  int b = bh >> 4, h = bh & 15;
  int lane = threadIdx.x;
  int hi = lane >> 5, ln = lane & 31;
  int q0 = qw * 32, qrow = q0 + ln;

  const u16* QPb = QP + ((size_t)(bh * 64 + qw) * 8) * 512 + lane * 8;
  short8 qf[8];
  #pragma unroll
  for (int ks = 0; ks < 8; ++ks) qf[ks] = *(const short8*)(QPb + ks * 512);

  f32x16 oc[4];
  #pragma unroll
  for (int db = 0; db < 4; ++db)
    #pragma unroll
    for (int r = 0; r < 16; ++r) oc[db][r] = 0.f;
  float mr = -3.0e38f, l = 0.f;

  const u16* KPb = KP + ((size_t)bh * 64 * 8) * 512 + lane * 8;  // + tt*4096 + ks*512
  const u16* VPb = VP + ((size_t)bh * 64 * 8) * 512 + lane * 8;  // + tt*4096 + (j2*4+db)*512

  int ntile = qw + 1;
  short8 kf[8];
  #pragma unroll
  for (int ks = 0; ks < 8; ++ks) kf[ks] = *(const short8*)(KPb + ks * 512);  // tile 0

  for (int tt = 0; tt < ntile; ++tt) {
    // V fragments for this tile (consumed after softmax — latency hidden)
    short8 va[8];
    #pragma unroll
    for (int u = 0; u < 8; ++u) va[u] = *(const short8*)(VPb + (size_t)tt * 4096 + u * 512);

    // S^T = K · Q
    f32x16 st;
    #pragma unroll
    for (int r = 0; r < 16; ++r) st[r] = 0.f;
    __builtin_amdgcn_s_setprio(1);
    #pragma unroll
    for (int ks = 0; ks < 8; ++ks)
      st = __builtin_amdgcn_mfma_f32_32x32x16_bf16(kf[ks], qf[ks], st, 0, 0, 0);
    __builtin_amdgcn_s_setprio(0);

    // prefetch next K tile (lands during softmax + PV)
    if (tt + 1 < ntile) {
      #pragma unroll
      for (int ks = 0; ks < 8; ++ks)
        kf[ks] = *(const short8*)(KPb + (size_t)(tt + 1) * 4096 + ks * 512);
    }

    int t0 = tt * 32;
    float sv[16];
    float pm = -3.0e38f;
    bool lastt = (tt == ntile - 1);
    #pragma unroll
    for (int r = 0; r < 16; ++r) {
      float x = st[r];
      if (lastt) {
        int t = t0 + (r & 3) + 8 * (r >> 2) + 4 * hi;
        x = (t <= qrow) ? x : -3.0e38f;
      }
      sv[r] = x;
    }
    #pragma unroll
    for (int r = 0; r < 15; r += 2) pm = fmaxf(fmaxf(pm, sv[r]), sv[r + 1]);
    pm = fmaxf(pm, sv[15]);
    pm = fmaxf(pm, __shfl_xor(pm, 32, 64));
    if (!__all(pm <= mr + 64.0f)) {
      float mnew = fmaxf(mr, pm);
      float al = exp2f((mr - mnew) * C2);
      l *= al;
      #pragma unroll
      for (int db = 0; db < 4; ++db)
        #pragma unroll
        for (int r = 0; r < 16; ++r) oc[db][r] *= al;
      mr = mnew;
    }
    float mc = mr * C2;
    float e[16];
    float rs = 0.f;
    #pragma unroll
    for (int r = 0; r < 16; ++r) {
      e[r] = exp2f(fmaf(sv[r], C2, -mc));
      rs += e[r];
    }
    rs += __shfl_xor(rs, 32, 64);
    l += rs;

    // P -> bf16 B-frags in-register (cvt_pk + permlane32_swap)
    unsigned w0 = cvtpk(e[0], e[1]),   w1 = cvtpk(e[2], e[3]);
    unsigned w2 = cvtpk(e[4], e[5]),   w3 = cvtpk(e[6], e[7]);
    unsigned w4 = cvtpk(e[8], e[9]),   w5 = cvtpk(e[10], e[11]);
    unsigned w6 = cvtpk(e[12], e[13]), w7 = cvtpk(e[14], e[15]);
    plswap(w0, w2); plswap(w1, w3); plswap(w4, w6); plswap(w5, w7);
    u32x4 pw0 = {w0, w1, w2, w3};
    u32x4 pw1 = {w4, w5, w6, w7};
    short8 pb0 = __builtin_bit_cast(short8, pw0);
    short8 pb1 = __builtin_bit_cast(short8, pw1);

    // O^T += V^T · P
    __builtin_amdgcn_s_setprio(1);
    #pragma unroll
    for (int db = 0; db < 4; ++db)
      oc[db] = __builtin_amdgcn_mfma_f32_32x32x16_bf16(va[db], pb0, oc[db], 0, 0, 0);
    #pragma unroll
    for (int db = 0; db < 4; ++db)
      oc[db] = __builtin_amdgcn_mfma_f32_32x32x16_bf16(va[4 + db], pb1, oc[db], 0, 0, 0);
    __builtin_amdgcn_s_setprio(0);
  }

  // epilogue: out[b][s=qrow][h*128 + d], d = db*32 + 8g + 4hi + j
  float inv = 1.0f / l;
  size_t ob = ((size_t)(b * S_LEN + qrow)) * HID + h * HD;
  #pragma unroll
  for (int db = 0; db < 4; ++db) {
    #pragma unroll
    for (int g = 0; g < 4; ++g) {
      u16x4 pk;
      #pragma unroll
      for (int j = 0; j < 4; ++j) pk[j] = f2bf(oc[db][4 * g + j] * inv);
      *(u16x4*)(out + ob + db * 32 + 8 * g + 4 * hi) = pk;
    }
  }
}

extern "C" void kernel_launch(void* const* d_in, const int* in_sizes, int n_in,
                              void* d_out, int out_size, void* d_ws, size_t ws_size,
                              hipStream_t stream) {
  const float* x    = (const float*)d_in[0];
  const float* rmsw = (const float*)d_in[1];
  const float* wq   = (const float*)d_in[2];
  const float* bq   = (const float*)d_in[3];
  const float* wk   = (const float*)d_in[4];
  const float* bk   = (const float*)d_in[5];
  const float* wv   = (const float*)d_in[6];
  const float* bv   = (const float*)d_in[7];
  const float* wo   = (const float*)d_in[8];
  const float* bo   = (const float*)d_in[9];

  char* ws = (char*)d_ws;
  const size_t SZ = (size_t)NROWS * HID * 2;  // 16 MB bf16 activation
  const size_t WSZ = (size_t)HID * HID * 2;   // 8 MB bf16 weight
  u16* xn   = (u16*)(ws);                     // 0-16 MB;  reused as QP
  u16* wqkT = (u16*)(ws + SZ);                // 16-40 MB; first 16 MB reused as KP
  u16* woT  = (u16*)(ws + SZ + 3 * WSZ);      // 40-48 MB, live till end
  u16* qhm  = (u16*)(ws + SZ + 4 * WSZ);      // 48-64 MB; reused as ao
  u16* khm  = (u16*)(ws + SZ + 4 * WSZ + SZ); // 64-80 MB; reused as VP
  u16* vhm  = (u16*)(ws + SZ + 4 * WSZ + 2 * SZ);  // 80-96 MB
  u16* QP   = xn;
  u16* KP   = wqkT;
  u16* VP   = khm;   // khm dead after ropepack
  u16* ao   = qhm;   // qhm dead after ropepack

  k_pre<<<dim3(8192), dim3(256), 0, stream>>>(x, rmsw, xn, wq, wk, wv, wo, wqkT);
  k_gemm_qkv2<<<dim3(768), dim3(512), 147456, stream>>>(xn, wqkT, bq, bk, bv, qhm);
  k_post<<<dim3(5120), dim3(256), 0, stream>>>(qhm, khm, QP, KP, vhm, VP);
  k_attn<<<dim3(2048), dim3(64), 0, stream>>>(QP, KP, VP, ao);
  k_gemm_o2<<<dim3(512), dim3(256), 49152, stream>>>(ao, woT, bo, x, (float*)d_out);
}

// Round 19
// 243.851 us; speedup vs baseline: 1.0916x; 1.0466x over previous
//
#include <hip/hip_runtime.h>
#include <stdint.h>
#include <math.h>

#define S_LEN 2048
#define HID 2048
#define NH 16
#define HD 128
#define NROWS 4096  // B*S
#define SCALE 0.08838834764831845f
#define C2 (0.08838834764831845f * 1.442695040888963f)  // SCALE * log2(e)

typedef unsigned short u16;
typedef __attribute__((ext_vector_type(8))) short short8;
typedef __attribute__((ext_vector_type(4))) float f32x4;
typedef __attribute__((ext_vector_type(16))) float f32x16;
typedef __attribute__((ext_vector_type(4))) unsigned short u16x4;
typedef __attribute__((ext_vector_type(4))) unsigned int u32x4;
typedef __attribute__((ext_vector_type(4))) float float4v;

__device__ __forceinline__ u16 f2bf(float f) {
  union { float f; uint32_t u; } v; v.f = f;
  uint32_t r = v.u + 0x7FFFu + ((v.u >> 16) & 1u);
  return (u16)(r >> 16);
}
__device__ __forceinline__ float bf2f(u16 b) {
  union { uint32_t u; float f; } v; v.u = ((uint32_t)b) << 16;
  return v.f;
}
__device__ __forceinline__ void gl_lds16(const void* g, void* l) {
  __builtin_amdgcn_global_load_lds((const __attribute__((address_space(1))) void*)g,
                                   (__attribute__((address_space(3))) void*)l, 16, 0, 0);
}
__device__ __forceinline__ unsigned cvtpk(float lo, float hi) {
  unsigned r;
  asm("v_cvt_pk_bf16_f32 %0, %1, %2" : "=v"(r) : "v"(lo), "v"(hi));
  return r;
}
__device__ __forceinline__ void plswap(unsigned &a, unsigned &b) {
  asm volatile("v_permlane32_swap_b32 %0, %1" : "+v"(a), "+v"(b));
}

// ---------- merged pre-pass: rmsnorm (blocks 0..4095) + wconv4 (blocks 4096..8191) ----------
__global__ __launch_bounds__(256) void k_pre(const float* __restrict__ x, const float* __restrict__ rw,
                                             u16* __restrict__ xn,
                                             const float* __restrict__ w0, const float* __restrict__ w1,
                                             const float* __restrict__ w2, const float* __restrict__ w3,
                                             u16* __restrict__ wtbase) {
  int bid = blockIdx.x;
  int tid = threadIdx.x;
  if (bid < 4096) {
    int row = bid;
    const float* xr = x + (size_t)row * HID;
    float4v a = *(const float4v*)(xr + tid * 8);
    float4v b = *(const float4v*)(xr + tid * 8 + 4);
    float s = a[0]*a[0] + a[1]*a[1] + a[2]*a[2] + a[3]*a[3]
            + b[0]*b[0] + b[1]*b[1] + b[2]*b[2] + b[3]*b[3];
    #pragma unroll
    for (int off = 1; off < 64; off <<= 1) s += __shfl_xor(s, off, 64);
    __shared__ float red[4];
    int wv = tid >> 6;
    if ((tid & 63) == 0) red[wv] = s;
    __syncthreads();
    float tot = red[0] + red[1] + red[2] + red[3];
    float r = rsqrtf(tot * (1.0f / HID) + 1e-5f);
    const float* wp = rw + tid * 8;
    u16x4 o0, o1;
    #pragma unroll
    for (int j = 0; j < 4; ++j) { o0[j] = f2bf(a[j] * r * wp[j]); o1[j] = f2bf(b[j] * r * wp[4 + j]); }
    *(u16x4*)(xn + (size_t)row * HID + tid * 8) = o0;
    *(u16x4*)(xn + (size_t)row * HID + tid * 8 + 4) = o1;
  } else {
    int c = bid - 4096;
    int z = c >> 10;
    int rest = c & 1023;
    int n0 = (rest & 31) * 64, k0 = (rest >> 5) * 64;
    const float* w = (z == 0) ? w0 : (z == 1) ? w1 : (z == 2) ? w2 : w3;
    u16* wt = wtbase + (size_t)z * HID * HID;
    __shared__ float t[64][68];
    int cr = tid >> 4;
    int cc = (tid & 15) * 4;
    #pragma unroll
    for (int it = 0; it < 4; ++it) {
      int kk = cr + it * 16;
      float4v v = *(const float4v*)(w + (size_t)(k0 + kk) * HID + n0 + cc);
      t[kk][cc] = v[0]; t[kk][cc + 1] = v[1]; t[kk][cc + 2] = v[2]; t[kk][cc + 3] = v[3];
    }
    __syncthreads();
    #pragma unroll
    for (int it = 0; it < 4; ++it) {
      int nn = cr + it * 16;
      u16x4 o;
      #pragma unroll
      for (int j = 0; j < 4; ++j) o[j] = f2bf(t[cc + j][nn]);
      *(u16x4*)(wt + (size_t)(n0 + nn) * HID + k0 + cc) = o;
    }
  }
}

// ---------- merged post-pass: ropepack (blocks 0..4095) + vpack (blocks 4096..5119) ----------
__global__ __launch_bounds__(256) void k_post(const u16* __restrict__ qh, const u16* __restrict__ kh,
                                              u16* __restrict__ QP, u16* __restrict__ KP,
                                              const u16* __restrict__ vh, u16* __restrict__ VP) {
  int bid = blockIdx.x;
  int tid = threadIdx.x;
  if (bid < 4096) {
    int l = tid & 63, wvv = tid >> 6;
    int rsub = l >> 4, c = l & 15;
    int row = bid * 16 + wvv * 4 + rsub;   // bh*2048 + s
    int bh = row >> 11, s = row & 2047;
    int tile = s >> 5, ln = s & 31;
    int ks = c >> 1, hi = c & 1;
    int k3 = ks & 3;
    const u16* qi = qh + (size_t)row * HD + 32 * k3 + 16 * hi;
    const u16* ki = kh + (size_t)row * HD + 32 * k3 + 16 * hi;
    float sn[8], cs[8];
    #pragma unroll
    for (int j = 0; j < 8; ++j) {
      int de = 16 * k3 + 8 * hi + j;
      float freq = exp2f((float)de * -0.20762050593046014f);  // theta^(-de/64)
      sincosf((float)s * freq, &sn[j], &cs[j]);
    }
    size_t off = ((((size_t)(bh * 64 + tile)) * 8 + ks) * 64 + hi * 32 + ln) * 8;
    {
      short8 a = *(const short8*)(qi);
      short8 b2 = *(const short8*)(qi + 8);
      u16x4 o0, o1;
      #pragma unroll
      for (int j = 0; j < 4; ++j) {
        float x0 = bf2f((u16)a[2 * j]), x1 = bf2f((u16)a[2 * j + 1]);
        o0[j] = f2bf((j & 1) ? (sn[j] * x0 + cs[j] * x1) : (cs[j] * x0 - sn[j] * x1));
      }
      #pragma unroll
      for (int j = 0; j < 4; ++j) {
        int jj = j + 4;
        float x0 = bf2f((u16)b2[2 * j]), x1 = bf2f((u16)b2[2 * j + 1]);
        o1[j] = f2bf((jj & 1) ? (sn[jj] * x0 + cs[jj] * x1) : (cs[jj] * x0 - sn[jj] * x1));
      }
      *(u16x4*)(QP + off) = o0; *(u16x4*)(QP + off + 4) = o1;
    }
    {
      short8 a = *(const short8*)(ki);
      short8 b2 = *(const short8*)(ki + 8);
      u16x4 o0, o1;
      #pragma unroll
      for (int j = 0; j < 4; ++j) {
        float x0 = bf2f((u16)a[2 * j]), x1 = bf2f((u16)a[2 * j + 1]);
        o0[j] = f2bf((j & 1) ? (sn[j] * x0 + cs[j] * x1) : (cs[j] * x0 - sn[j] * x1));
      }
      #pragma unroll
      for (int j = 0; j < 4; ++j) {
        int jj = j + 4;
        float x0 = bf2f((u16)b2[2 * j]), x1 = bf2f((u16)b2[2 * j + 1]);
        o1[j] = f2bf((jj & 1) ? (sn[jj] * x0 + cs[jj] * x1) : (cs[jj] * x0 - sn[jj] * x1));
      }
      *(u16x4*)(KP + off) = o0; *(u16x4*)(KP + off + 4) = o1;
    }
  } else {
    int c = bid - 4096;           // 0..1023
    int bx = c & 31;              // s-tile of 64
    int bh = c >> 5;
    __shared__ u16 t[64][136];
    int row = tid >> 2;
    int d0 = (tid & 3) * 32;
    const u16* src = vh + ((size_t)bh * S_LEN + bx * 64 + row) * HD + d0;
    short8 a = *(const short8*)(src);
    short8 b = *(const short8*)(src + 8);
    short8 cc2 = *(const short8*)(src + 16);
    short8 d = *(const short8*)(src + 24);
    *(short8*)(&t[row][d0]) = a;
    *(short8*)(&t[row][d0 + 8]) = b;
    *(short8*)(&t[row][d0 + 16]) = cc2;
    *(short8*)(&t[row][d0 + 24]) = d;
    __syncthreads();
    #pragma unroll
    for (int i = 0; i < 4; ++i) {
      int cid = i * 256 + tid;        // chunk id 0..1023
      int lp = cid & 63;
      int db = (cid >> 6) & 3;
      int j2 = (cid >> 8) & 1;
      int tl = (cid >> 9) & 1;
      int tg = bx * 2 + tl;
      int tloc = tl * 32 + j2 * 16 + (lp >> 5) * 8;
      int dloc = db * 32 + (lp & 31);
      short8 v;
      #pragma unroll
      for (int jj = 0; jj < 8; ++jj) v[jj] = (short)t[tloc + jj][dloc];
      size_t off = ((((size_t)(bh * 64 + tg) * 2 + j2) * 4 + db) * 64 + lp) * 8;
      *(short8*)(VP + off) = v;
    }
  }
}

// ---------- deep-pipelined QKV GEMM: C[4096][6144] = A[4096][2048] * BT[6144][2048] ----------
// BM=128, BN=256, 8 waves (2x4), per-wave 64x64, BK=64. 3-slot LDS ring of 48 KB K-tiles
// (144 KB -> 1 block/CU). Per K-tile: 2 phases x 16 MFMA (A-frags hoisted in q0).
// Stage t+2 per phase (q0: A+B0, q1: B1); vmcnt(6) at even-phase tops (vmcnt(0) at t=31).
// Swizzle: chunk ^= row&7 (involution; 2-way banks = free). Head-major bf16 output.
__global__ __launch_bounds__(512, 1) void k_gemm_qkv2(const u16* __restrict__ A, const u16* __restrict__ BT,
                                                      const float* __restrict__ bq, const float* __restrict__ bk,
                                                      const float* __restrict__ bv, u16* __restrict__ qkv) {
  extern __shared__ __align__(16) char smraw[];
  u16* sm = (u16*)smraw;     // 3 slots x 24576 u16 (A:[128][64]=8192 + B:[256][64]=16384)
  int bid = blockIdx.x;      // 768 blocks
  int xcd = bid & 7, loc = bid >> 3;
  int bx = xcd * 3 + loc % 3;     // 0..23 (N-block of 256)
  int by = loc / 3;               // 0..31 (M-block of 128)
  int tid = threadIdx.x;
  int w = tid >> 6, lane = tid & 63;
  int wr = w >> 2, wc = w & 3;    // 2 x 4 waves
  int lq = lane & 15, lg = lane >> 4;

  f32x4 acc[4][4];
  #pragma unroll
  for (int mi = 0; mi < 4; ++mi)
    #pragma unroll
    for (int ni = 0; ni < 4; ++ni) acc[mi][ni] = (f32x4){0.f, 0.f, 0.f, 0.f};

  const size_t Abase = (size_t)(by * 128) * HID;
  const size_t Bbase = (size_t)(bx * 256) * HID;

  #define STAGE_A(n)  do { \
    int slot_ = ((n) % 3) * 24576; \
    int kb_ = (n) * 64; \
    _Pragma("unroll") \
    for (int it_ = 0; it_ < 2; ++it_) { \
      int c_ = it_ * 512 + tid; int row_ = c_ >> 3; int cs_ = (c_ & 7) ^ (row_ & 7); \
      gl_lds16(A + Abase + (size_t)row_ * HID + kb_ + cs_ * 8, sm + slot_ + c_ * 8); } \
  } while (0)
  #define STAGE_B(n, h)  do { \
    int slot_ = ((n) % 3) * 24576; \
    int kb_ = (n) * 64; \
    _Pragma("unroll") \
    for (int it_ = 0; it_ < 2; ++it_) { \
      int c_ = it_ * 512 + tid; int row_ = c_ >> 3; int cs_ = (c_ & 7) ^ (row_ & 7); \
      gl_lds16(BT + Bbase + (size_t)(128 * (h) + row_) * HID + kb_ + cs_ * 8, \
               sm + slot_ + 8192 + 8192 * (h) + c_ * 8); } \
  } while (0)

  STAGE_A(0); STAGE_B(0, 0); STAGE_B(0, 1);
  STAGE_A(1); STAGE_B(1, 0); STAGE_B(1, 1);
  asm volatile("s_waitcnt vmcnt(6)" ::: "memory");   // tile 0 landed
  __builtin_amdgcn_s_barrier();
  __builtin_amdgcn_sched_barrier(0);

  for (int t = 0; t < 32; ++t) {
    int slot = (t % 3) * 24576;
    const u16* sA = sm + slot;
    const u16* sB = sm + slot + 8192;   // [256][64]
    // ---- phase q0 ----
    if (t == 31) asm volatile("s_waitcnt vmcnt(0)" ::: "memory");
    else         asm volatile("s_waitcnt vmcnt(6)" ::: "memory");
    short8 af[4][2], bf0[2][2];
    #pragma unroll
    for (int mi = 0; mi < 4; ++mi) {
      int ra = wr * 64 + mi * 16 + lq;
      #pragma unroll
      for (int ks = 0; ks < 2; ++ks)
        af[mi][ks] = *(const short8*)(sA + ra * 64 + (((ks * 4 + lg) ^ (ra & 7)) << 3));
    }
    #pragma unroll
    for (int nl = 0; nl < 2; ++nl) {
      int rb = wc * 64 + nl * 16 + lq;
      #pragma unroll
      for (int ks = 0; ks < 2; ++ks)
        bf0[nl][ks] = *(const short8*)(sB + rb * 64 + (((ks * 4 + lg) ^ (rb & 7)) << 3));
    }
    if (t + 2 < 32) { STAGE_A(t + 2); STAGE_B(t + 2, 0); }
    __builtin_amdgcn_s_setprio(1);
    #pragma unroll
    for (int ks = 0; ks < 2; ++ks)
      #pragma unroll
      for (int mi = 0; mi < 4; ++mi)
        #pragma unroll
        for (int nl = 0; nl < 2; ++nl)
          acc[mi][nl] = __builtin_amdgcn_mfma_f32_16x16x32_bf16(af[mi][ks], bf0[nl][ks], acc[mi][nl], 0, 0, 0);
    __builtin_amdgcn_s_setprio(0);
    __builtin_amdgcn_s_barrier();
    __builtin_amdgcn_sched_barrier(0);
    // ---- phase q1 ----
    short8 bf1[2][2];
    #pragma unroll
    for (int nl = 0; nl < 2; ++nl) {
      int rb = wc * 64 + (nl + 2) * 16 + lq;
      #pragma unroll
      for (int ks = 0; ks < 2; ++ks)
        bf1[nl][ks] = *(const short8*)(sB + rb * 64 + (((ks * 4 + lg) ^ (rb & 7)) << 3));
    }
    if (t + 2 < 32) STAGE_B(t + 2, 1);
    __builtin_amdgcn_s_setprio(1);
    #pragma unroll
    for (int ks = 0; ks < 2; ++ks)
      #pragma unroll
      for (int mi = 0; mi < 4; ++mi)
        #pragma unroll
        for (int nl = 0; nl < 2; ++nl)
          acc[mi][nl + 2] = __builtin_amdgcn_mfma_f32_16x16x32_bf16(af[mi][ks], bf1[nl][ks], acc[mi][nl + 2], 0, 0, 0);
    __builtin_amdgcn_s_setprio(0);
    __builtin_amdgcn_s_barrier();
    __builtin_amdgcn_sched_barrier(0);
  }

  #pragma unroll
  for (int ni = 0; ni < 4; ++ni) {
    int colg = bx * 256 + wc * 64 + ni * 16 + lq;   // 0..6143
    int sel = colg >> 11;
    int col = colg & 2047;
    int h = col >> 7, d = col & 127;
    const float* bias = (sel == 0) ? bq : (sel == 1) ? bk : bv;
    float bs = bias[col];
    u16* outp = qkv + (size_t)sel * NROWS * HID;
    #pragma unroll
    for (int mi = 0; mi < 4; ++mi) {
      #pragma unroll
      for (int r = 0; r < 4; ++r) {
        int rowm = by * 128 + wr * 64 + mi * 16 + lg * 4 + r;
        int b = rowm >> 11, s = rowm & 2047;
        outp[(((size_t)(b * NH + h)) * S_LEN + s) * HD + d] = f2bf(acc[mi][ni][r] + bs);
      }
    }
  }
  #undef STAGE_A
  #undef STAGE_B
}

// ---------- deep-pipelined output GEMM: C[4096][2048] f32 = A*BT + bias + resid ----------
// Same structure as k_gemm_qkv2; grid 256 (1/CU, bx = xcd -> one 256-col B-panel per XCD).
__global__ __launch_bounds__(512, 1) void k_gemm_o2(const u16* __restrict__ A, const u16* __restrict__ BT,
                                                    const float* __restrict__ bias,
                                                    const float* __restrict__ resid,
                                                    float* __restrict__ outp) {
  extern __shared__ __align__(16) char smraw[];
  u16* sm = (u16*)smraw;     // 3 slots x 24576 u16
  int bid = blockIdx.x;      // 256 blocks
  int bx = bid & 7;          // 0..7 (N-block of 256) = XCD
  int by = bid >> 3;         // 0..31 (M-block of 128)
  int tid = threadIdx.x;
  int w = tid >> 6, lane = tid & 63;
  int wr = w >> 2, wc = w & 3;
  int lq = lane & 15, lg = lane >> 4;

  f32x4 acc[4][4];
  #pragma unroll
  for (int mi = 0; mi < 4; ++mi)
    #pragma unroll
    for (int ni = 0; ni < 4; ++ni) acc[mi][ni] = (f32x4){0.f, 0.f, 0.f, 0.f};

  const size_t Abase = (size_t)(by * 128) * HID;
  const size_t Bbase = (size_t)(bx * 256) * HID;

  #define STAGE_A(n)  do { \
    int slot_ = ((n) % 3) * 24576; \
    int kb_ = (n) * 64; \
    _Pragma("unroll") \
    for (int it_ = 0; it_ < 2; ++it_) { \
      int c_ = it_ * 512 + tid; int row_ = c_ >> 3; int cs_ = (c_ & 7) ^ (row_ & 7); \
      gl_lds16(A + Abase + (size_t)row_ * HID + kb_ + cs_ * 8, sm + slot_ + c_ * 8); } \
  } while (0)
  #define STAGE_B(n, h)  do { \
    int slot_ = ((n) % 3) * 24576; \
    int kb_ = (n) * 64; \
    _Pragma("unroll") \
    for (int it_ = 0; it_ < 2; ++it_) { \
      int c_ = it_ * 512 + tid; int row_ = c_ >> 3; int cs_ = (c_ & 7) ^ (row_ & 7); \
      gl_lds16(BT + Bbase + (size_t)(128 * (h) + row_) * HID + kb_ + cs_ * 8, \
               sm + slot_ + 8192 + 8192 * (h) + c_ * 8); } \
  } while (0)

  STAGE_A(0); STAGE_B(0, 0); STAGE_B(0, 1);
  STAGE_A(1); STAGE_B(1, 0); STAGE_B(1, 1);
  asm volatile("s_waitcnt vmcnt(6)" ::: "memory");
  __builtin_amdgcn_s_barrier();
  __builtin_amdgcn_sched_barrier(0);

  for (int t = 0; t < 32; ++t) {
    int slot = (t % 3) * 24576;
    const u16* sA = sm + slot;
    const u16* sB = sm + slot + 8192;
    if (t == 31) asm volatile("s_waitcnt vmcnt(0)" ::: "memory");
    else         asm volatile("s_waitcnt vmcnt(6)" ::: "memory");
    short8 af[4][2], bf0[2][2];
    #pragma unroll
    for (int mi = 0; mi < 4; ++mi) {
      int ra = wr * 64 + mi * 16 + lq;
      #pragma unroll
      for (int ks = 0; ks < 2; ++ks)
        af[mi][ks] = *(const short8*)(sA + ra * 64 + (((ks * 4 + lg) ^ (ra & 7)) << 3));
    }
    #pragma unroll
    for (int nl = 0; nl < 2; ++nl) {
      int rb = wc * 64 + nl * 16 + lq;
      #pragma unroll
      for (int ks = 0; ks < 2; ++ks)
        bf0[nl][ks] = *(const short8*)(sB + rb * 64 + (((ks * 4 + lg) ^ (rb & 7)) << 3));
    }
    if (t + 2 < 32) { STAGE_A(t + 2); STAGE_B(t + 2, 0); }
    __builtin_amdgcn_s_setprio(1);
    #pragma unroll
    for (int ks = 0; ks < 2; ++ks)
      #pragma unroll
      for (int mi = 0; mi < 4; ++mi)
        #pragma unroll
        for (int nl = 0; nl < 2; ++nl)
          acc[mi][nl] = __builtin_amdgcn_mfma_f32_16x16x32_bf16(af[mi][ks], bf0[nl][ks], acc[mi][nl], 0, 0, 0);
    __builtin_amdgcn_s_setprio(0);
    __builtin_amdgcn_s_barrier();
    __builtin_amdgcn_sched_barrier(0);
    short8 bf1[2][2];
    #pragma unroll
    for (int nl = 0; nl < 2; ++nl) {
      int rb = wc * 64 + (nl + 2) * 16 + lq;
      #pragma unroll
      for (int ks = 0; ks < 2; ++ks)
        bf1[nl][ks] = *(const short8*)(sB + rb * 64 + (((ks * 4 + lg) ^ (rb & 7)) << 3));
    }
    if (t + 2 < 32) STAGE_B(t + 2, 1);
    __builtin_amdgcn_s_setprio(1);
    #pragma unroll
    for (int ks = 0; ks < 2; ++ks)
      #pragma unroll
      for (int mi = 0; mi < 4; ++mi)
        #pragma unroll
        for (int nl = 0; nl < 2; ++nl)
          acc[mi][nl + 2] = __builtin_amdgcn_mfma_f32_16x16x32_bf16(af[mi][ks], bf1[nl][ks], acc[mi][nl + 2], 0, 0, 0);
    __builtin_amdgcn_s_setprio(0);
    __builtin_amdgcn_s_barrier();
    __builtin_amdgcn_sched_barrier(0);
  }

  #pragma unroll
  for (int ni = 0; ni < 4; ++ni) {
    int col = bx * 256 + wc * 64 + ni * 16 + lq;   // 0..2047
    float bs = bias[col];
    #pragma unroll
    for (int mi = 0; mi < 4; ++mi) {
      #pragma unroll
      for (int r = 0; r < 4; ++r) {
        int rowm = by * 128 + wr * 64 + mi * 16 + lg * 4 + r;
        size_t o = (size_t)rowm * HID + col;
        outp[o] = acc[mi][ni][r] + bs + resid[o];
      }
    }
  }
  #undef STAGE_A
  #undef STAGE_B
}

// ---------- flash attention v6: barrier-free, LDS-free, packed fragment loads ----------
// QP,KP: [bh][tile][ks(8)][lane][8]; VP: [bh][tile][j2(2)][db(4)][lane][8]; out bf16 [b][s][h*128+d]
__global__ __launch_bounds__(64, 2) void k_attn(const u16* __restrict__ QP, const u16* __restrict__ KP,
                                                const u16* __restrict__ VP, u16* __restrict__ out) {
  int bid = blockIdx.x;            // 2048 one-wave blocks
  int rest = bid >> 3;
  int bh = (bid & 7) * 4 + (rest & 3);   // 4 heads per XCD
  int gg = rest >> 2;                    // 0..63
  int qw = (gg < 32) ? (63 - gg) : (gg - 32);  // complement-paired for balance
  int b = bh >> 4, h = bh & 15;
  int lane = threadIdx.x;
  int hi = lane >> 5, ln = lane & 31;
  int q0 = qw * 32, qrow = q0 + ln;

  const u16* QPb = QP + ((size_t)(bh * 64 + qw) * 8) * 512 + lane * 8;
  short8 qf[8];
  #pragma unroll
  for (int ks = 0; ks < 8; ++ks) qf[ks] = *(const short8*)(QPb + ks * 512);

  f32x16 oc[4];
  #pragma unroll
  for (int db = 0; db < 4; ++db)
    #pragma unroll
    for (int r = 0; r < 16; ++r) oc[db][r] = 0.f;
  float mr = -3.0e38f, l = 0.f;

  const u16* KPb = KP + ((size_t)bh * 64 * 8) * 512 + lane * 8;  // + tt*4096 + ks*512
  const u16* VPb = VP + ((size_t)bh * 64 * 8) * 512 + lane * 8;  // + tt*4096 + (j2*4+db)*512

  int ntile = qw + 1;
  short8 kf[8];
  #pragma unroll
  for (int ks = 0; ks < 8; ++ks) kf[ks] = *(const short8*)(KPb + ks * 512);  // tile 0

  for (int tt = 0; tt < ntile; ++tt) {
    // V fragments for this tile (consumed after softmax — latency hidden)
    short8 va[8];
    #pragma unroll
    for (int u = 0; u < 8; ++u) va[u] = *(const short8*)(VPb + (size_t)tt * 4096 + u * 512);

    // S^T = K · Q
    f32x16 st;
    #pragma unroll
    for (int r = 0; r < 16; ++r) st[r] = 0.f;
    __builtin_amdgcn_s_setprio(1);
    #pragma unroll
    for (int ks = 0; ks < 8; ++ks)
      st = __builtin_amdgcn_mfma_f32_32x32x16_bf16(kf[ks], qf[ks], st, 0, 0, 0);
    __builtin_amdgcn_s_setprio(0);

    // prefetch next K tile (lands during softmax + PV)
    if (tt + 1 < ntile) {
      #pragma unroll
      for (int ks = 0; ks < 8; ++ks)
        kf[ks] = *(const short8*)(KPb + (size_t)(tt + 1) * 4096 + ks * 512);
    }

    int t0 = tt * 32;
    float sv[16];
    float pm = -3.0e38f;
    bool lastt = (tt == ntile - 1);
    #pragma unroll
    for (int r = 0; r < 16; ++r) {
      float x = st[r];
      if (lastt) {
        int t = t0 + (r & 3) + 8 * (r >> 2) + 4 * hi;
        x = (t <= qrow) ? x : -3.0e38f;
      }
      sv[r] = x;
    }
    #pragma unroll
    for (int r = 0; r < 15; r += 2) pm = fmaxf(fmaxf(pm, sv[r]), sv[r + 1]);
    pm = fmaxf(pm, sv[15]);
    pm = fmaxf(pm, __shfl_xor(pm, 32, 64));
    if (!__all(pm <= mr + 64.0f)) {
      float mnew = fmaxf(mr, pm);
      float al = exp2f((mr - mnew) * C2);
      l *= al;
      #pragma unroll
      for (int db = 0; db < 4; ++db)
        #pragma unroll
        for (int r = 0; r < 16; ++r) oc[db][r] *= al;
      mr = mnew;
    }
    float mc = mr * C2;
    float e[16];
    float rs = 0.f;
    #pragma unroll
    for (int r = 0; r < 16; ++r) {
      e[r] = exp2f(fmaf(sv[r], C2, -mc));
      rs += e[r];
    }
    rs += __shfl_xor(rs, 32, 64);
    l += rs;

    // P -> bf16 B-frags in-register (cvt_pk + permlane32_swap)
    unsigned w0 = cvtpk(e[0], e[1]),   w1 = cvtpk(e[2], e[3]);
    unsigned w2 = cvtpk(e[4], e[5]),   w3 = cvtpk(e[6], e[7]);
    unsigned w4 = cvtpk(e[8], e[9]),   w5 = cvtpk(e[10], e[11]);
    unsigned w6 = cvtpk(e[12], e[13]), w7 = cvtpk(e[14], e[15]);
    plswap(w0, w2); plswap(w1, w3); plswap(w4, w6); plswap(w5, w7);
    u32x4 pw0 = {w0, w1, w2, w3};
    u32x4 pw1 = {w4, w5, w6, w7};
    short8 pb0 = __builtin_bit_cast(short8, pw0);
    short8 pb1 = __builtin_bit_cast(short8, pw1);

    // O^T += V^T · P
    __builtin_amdgcn_s_setprio(1);
    #pragma unroll
    for (int db = 0; db < 4; ++db)
      oc[db] = __builtin_amdgcn_mfma_f32_32x32x16_bf16(va[db], pb0, oc[db], 0, 0, 0);
    #pragma unroll
    for (int db = 0; db < 4; ++db)
      oc[db] = __builtin_amdgcn_mfma_f32_32x32x16_bf16(va[4 + db], pb1, oc[db], 0, 0, 0);
    __builtin_amdgcn_s_setprio(0);
  }

  // epilogue: out[b][s=qrow][h*128 + d], d = db*32 + 8g + 4hi + j
  float inv = 1.0f / l;
  size_t ob = ((size_t)(b * S_LEN + qrow)) * HID + h * HD;
  #pragma unroll
  for (int db = 0; db < 4; ++db) {
    #pragma unroll
    for (int g = 0; g < 4; ++g) {
      u16x4 pk;
      #pragma unroll
      for (int j = 0; j < 4; ++j) pk[j] = f2bf(oc[db][4 * g + j] * inv);
      *(u16x4*)(out + ob + db * 32 + 8 * g + 4 * hi) = pk;
    }
  }
}

extern "C" void kernel_launch(void* const* d_in, const int* in_sizes, int n_in,
                              void* d_out, int out_size, void* d_ws, size_t ws_size,
                              hipStream_t stream) {
  const float* x    = (const float*)d_in[0];
  const float* rmsw = (const float*)d_in[1];
  const float* wq   = (const float*)d_in[2];
  const float* bq   = (const float*)d_in[3];
  const float* wk   = (const float*)d_in[4];
  const float* bk   = (const float*)d_in[5];
  const float* wv   = (const float*)d_in[6];
  const float* bv   = (const float*)d_in[7];
  const float* wo   = (const float*)d_in[8];
  const float* bo   = (const float*)d_in[9];

  char* ws = (char*)d_ws;
  const size_t SZ = (size_t)NROWS * HID * 2;  // 16 MB bf16 activation
  const size_t WSZ = (size_t)HID * HID * 2;   // 8 MB bf16 weight
  u16* xn   = (u16*)(ws);                     // 0-16 MB;  reused as QP
  u16* wqkT = (u16*)(ws + SZ);                // 16-40 MB; first 16 MB reused as KP
  u16* woT  = (u16*)(ws + SZ + 3 * WSZ);      // 40-48 MB, live till end
  u16* qhm  = (u16*)(ws + SZ + 4 * WSZ);      // 48-64 MB; reused as ao
  u16* khm  = (u16*)(ws + SZ + 4 * WSZ + SZ); // 64-80 MB; reused as VP
  u16* vhm  = (u16*)(ws + SZ + 4 * WSZ + 2 * SZ);  // 80-96 MB
  u16* QP   = xn;
  u16* KP   = wqkT;
  u16* VP   = khm;   // khm dead after ropepack
  u16* ao   = qhm;   // qhm dead after ropepack

  k_pre<<<dim3(8192), dim3(256), 0, stream>>>(x, rmsw, xn, wq, wk, wv, wo, wqkT);
  k_gemm_qkv2<<<dim3(768), dim3(512), 147456, stream>>>(xn, wqkT, bq, bk, bv, qhm);
  k_post<<<dim3(5120), dim3(256), 0, stream>>>(qhm, khm, QP, KP, vhm, VP);
  k_attn<<<dim3(2048), dim3(64), 0, stream>>>(QP, KP, VP, ao);
  k_gemm_o2<<<dim3(256), dim3(512), 147456, stream>>>(ao, woT, bo, x, (float*)d_out);
}